// Round 4
// baseline (1872.192 us; speedup 1.0000x reference)
//
#include <hip/hip_runtime.h>
#include <stdint.h>

typedef __bf16 bf16x8 __attribute__((ext_vector_type(8)));
typedef __bf16 bf16x4 __attribute__((ext_vector_type(4)));
typedef float  f32x4  __attribute__((ext_vector_type(4)));
typedef unsigned int u32;

__device__ __forceinline__ void gl_lds16(const void* gptr, void* lptr) {
    __builtin_amdgcn_global_load_lds(
        (const __attribute__((address_space(1))) u32*)gptr,
        (__attribute__((address_space(3))) u32*)lptr,
        16, 0, 0);
}

__device__ __forceinline__ float gelu_exact(float x) {
    return 0.5f * x * (1.0f + erff(x * 0.70710678118654752f));
}

// compiler-level reorder fence (no instructions emitted)
#define MEMFENCE __asm__ __volatile__("" ::: "memory")

__global__ void zero_out(float* __restrict__ o, int n) {
    int i = blockIdx.x * 256 + threadIdx.x;
    if (i < n) o[i] = 0.0f;
}

// ---------------------------------------------------------------------------
// fp32 [K][N] -> bf16 transposed [N][K]
// ---------------------------------------------------------------------------
__global__ __launch_bounds__(256)
void transpose_to_bf16(const float* __restrict__ src, __bf16* __restrict__ dst,
                       int K, int Ncols) {
    __shared__ float tile[64][65];
    const int bk = blockIdx.x * 64;
    const int bn = blockIdx.y * 64;
    const int tid = threadIdx.x;
    const int tr = tid >> 4;
    const int tc = (tid & 15) * 4;
#pragma unroll
    for (int p = 0; p < 4; ++p) {
        const int r = tr + p * 16;
        float4 v = *(const float4*)&src[(size_t)(bk + r) * Ncols + bn + tc];
        tile[r][tc] = v.x; tile[r][tc + 1] = v.y;
        tile[r][tc + 2] = v.z; tile[r][tc + 3] = v.w;
    }
    __syncthreads();
#pragma unroll
    for (int p = 0; p < 4; ++p) {
        const int rn = tr + p * 16;
        bf16x4 o;
        o[0] = (__bf16)tile[tc + 0][rn];
        o[1] = (__bf16)tile[tc + 1][rn];
        o[2] = (__bf16)tile[tc + 2][rn];
        o[3] = (__bf16)tile[tc + 3][rn];
        *(bf16x4*)&dst[(size_t)(bn + rn) * K + bk + tc] = o;
    }
}

__global__ void f32_to_bf16(const float* __restrict__ s, __bf16* __restrict__ d, int n) {
    int idx = blockIdx.x * 256 + threadIdx.x;
    if (idx * 4 < n) {
        float4 v = *(const float4*)(s + idx * 4);
        bf16x4 o;
        o[0] = (__bf16)v.x; o[1] = (__bf16)v.y; o[2] = (__bf16)v.z; o[3] = (__bf16)v.w;
        *(bf16x4*)(d + idx * 4) = o;
    }
}

// ---------------------------------------------------------------------------
// feat bf16 [CM][1536] = [ x_i | x_j | rbf(dist)@rbf_W + rbf_b ]
// ---------------------------------------------------------------------------
__global__ __launch_bounds__(256)
void build_feat(const float* __restrict__ x, const float* __restrict__ dist,
                const __bf16* __restrict__ rbfW, const float* __restrict__ rbf_b,
                __bf16* __restrict__ feat, int m0) {
    __shared__ __align__(16) __bf16 Wl[50 * 512];
    __shared__ float gl[16][52];

    const int tid = threadIdx.x;
    const int mloc0 = blockIdx.x * 16;
    const int mg0 = m0 + mloc0;

    {
        const uint2* s = (const uint2*)rbfW;
        uint2* d = (uint2*)Wl;
#pragma unroll
        for (int c = 0; c < 25; ++c) d[tid + c * 256] = s[tid + c * 256];
    }
    const float spacing = 12.0f / 49.0f;
    const float coeff = -0.5f / (spacing * spacing);
    for (int idx = tid; idx < 16 * 50; idx += 256) {
        int r = idx / 50, k = idx - r * 50;
        float d = dist[mg0 + r];
        float t = d - (float)k * spacing;
        gl[r][k] = __expf(coeff * t * t);
    }
    __syncthreads();

    const int r = tid >> 4;
    const int ebase = (tid & 15) * 8;

    const int mg = mg0 + r;
    const int i = mg >> 8;
    const int j = (mg >> 1) & 127;
    const int b = mg & 1;

    __bf16* frow = feat + (size_t)(mloc0 + r) * 1536;
    const float* xi = x + ((size_t)i * 2 + b) * 512;
    const float* xj = x + ((size_t)j * 2 + b) * 512;

#pragma unroll
    for (int t8 = 0; t8 < 4; ++t8) {
        const int e = ebase + t8 * 128;
        float4 a0 = *(const float4*)(xi + e);
        float4 a1 = *(const float4*)(xi + e + 4);
        bf16x8 v;
        v[0]=(__bf16)a0.x; v[1]=(__bf16)a0.y; v[2]=(__bf16)a0.z; v[3]=(__bf16)a0.w;
        v[4]=(__bf16)a1.x; v[5]=(__bf16)a1.y; v[6]=(__bf16)a1.z; v[7]=(__bf16)a1.w;
        *(bf16x8*)(frow + e) = v;
        float4 b0 = *(const float4*)(xj + e);
        float4 b1 = *(const float4*)(xj + e + 4);
        bf16x8 u;
        u[0]=(__bf16)b0.x; u[1]=(__bf16)b0.y; u[2]=(__bf16)b0.z; u[3]=(__bf16)b0.w;
        u[4]=(__bf16)b1.x; u[5]=(__bf16)b1.y; u[6]=(__bf16)b1.z; u[7]=(__bf16)b1.w;
        *(bf16x8*)(frow + 512 + e) = u;
    }

    float acc[4][8];
#pragma unroll
    for (int t8 = 0; t8 < 4; ++t8)
#pragma unroll
        for (int q = 0; q < 8; ++q) acc[t8][q] = rbf_b[ebase + t8 * 128 + q];

    for (int k = 0; k < 50; ++k) {
        const float gk = gl[r][k];
#pragma unroll
        for (int t8 = 0; t8 < 4; ++t8) {
            bf16x8 wv = *(const bf16x8*)(Wl + k * 512 + ebase + t8 * 128);
#pragma unroll
            for (int q = 0; q < 8; ++q) acc[t8][q] += gk * (float)wv[q];
        }
    }
#pragma unroll
    for (int t8 = 0; t8 < 4; ++t8) {
        bf16x8 v;
#pragma unroll
        for (int q = 0; q < 8; ++q) v[q] = (__bf16)acc[t8][q];
        *(bf16x8*)(frow + 1024 + ebase + t8 * 128) = v;
    }
}

// ---------------------------------------------------------------------------
// GEMM, 3-stage LDS pipeline, raw s_barrier + manual vmcnt (prefetch never
// drained). 1-D grid, bn-fast decode for A-panel reuse.
//   CAT : N=2048, bn>=8 -> C1/bias1 (layer-0 e|f merged), NBN=16
//   RES : v = gelu(acc+b) + A[gm][gn]
//   HEAD: partial dots per (bn,wn) -> dotArr[(bn*2+wn)*32768 + m] plain stores
// ---------------------------------------------------------------------------
template <bool RES, bool CAT, bool HEAD>
__global__ __launch_bounds__(256)
void gemm_fused(const __bf16* __restrict__ A, const __bf16* __restrict__ Bt,
                const float* __restrict__ bias0, const float* __restrict__ bias1,
                __bf16* __restrict__ C0, __bf16* __restrict__ C1,
                const float* __restrict__ wout, float* __restrict__ dotArr,
                int K) {
    constexpr int NBN = CAT ? 16 : 8;
    constexpr int NBS = CAT ? 4 : 3;
    __shared__ __align__(16) __bf16 As[3][128 * 32];   // 3 x 8 KB
    __shared__ __align__(16) __bf16 Bs[3][128 * 32];   // 3 x 8 KB

    const int tid = threadIdx.x;
    const int flat = blockIdx.x;
    const int bn = flat & (NBN - 1);     // fast dim: all bn of one A-panel together
    const int bm = flat >> NBS;
    const int w = tid >> 6;
    const int lane = tid & 63;

    const int r0 = tid >> 2;
    const int s0 = tid & 3;
    const size_t Kb = (size_t)K * 2;
    const char* gA0 = (const char*)A + (size_t)(bm * 128 + r0) * Kb + s0 * 16;
    const char* gA1 = gA0 + 64 * Kb;
    const char* gB0 = (const char*)Bt + (size_t)(bn * 128 + r0) * Kb + s0 * 16;
    const char* gB1 = gB0 + 64 * Kb;

    char* lA[3] = { (char*)&As[0][0] + w * 1024, (char*)&As[1][0] + w * 1024,
                    (char*)&As[2][0] + w * 1024 };
    char* lB[3] = { (char*)&Bs[0][0] + w * 1024, (char*)&Bs[1][0] + w * 1024,
                    (char*)&Bs[2][0] + w * 1024 };

    const int wm = (w >> 1) & 1;
    const int wn = w & 1;
    const int lm = lane & 15;
    const int ko = (lane >> 4) << 3;
    const int fo = (wm * 64 + lm) * 32 + ko;
    const int go = (wn * 64 + lm) * 32 + ko;

    f32x4 acc[4][4];
    const f32x4 zero = {0.0f, 0.0f, 0.0f, 0.0f};
#pragma unroll
    for (int i = 0; i < 4; ++i)
#pragma unroll
        for (int j = 0; j < 4; ++j) acc[i][j] = zero;

    auto stage = [&](int buf) {
        gl_lds16(gA0, lA[buf]); gl_lds16(gA1, lA[buf] + 4096);
        gl_lds16(gB0, lB[buf]); gl_lds16(gB1, lB[buf] + 4096);
        gA0 += 64; gA1 += 64; gB0 += 64; gB1 += 64;
    };
    auto compute = [&](int buf) {
        bf16x8 af[4], bfg[4];
        const __bf16* pa = &As[buf][0] + fo;
        const __bf16* pb = &Bs[buf][0] + go;
#pragma unroll
        for (int i = 0; i < 4; ++i) {
            af[i]  = *(const bf16x8*)(pa + i * 512);
            bfg[i] = *(const bf16x8*)(pb + i * 512);
        }
#pragma unroll
        for (int mi = 0; mi < 4; ++mi)
#pragma unroll
            for (int ni = 0; ni < 4; ++ni)
                acc[mi][ni] = __builtin_amdgcn_mfma_f32_16x16x32_bf16(
                    af[mi], bfg[ni], acc[mi][ni], 0, 0, 0);
    };

    const int nk = K >> 5;   // 32 or 48
    stage(0);
    stage(1);
    int bufS = 2, bufC = 0;
    for (int kb = 0; kb < nk - 2; ++kb) {
        stage(bufS); bufS = (bufS == 2) ? 0 : bufS + 1;
        MEMFENCE;
        __builtin_amdgcn_s_waitcnt(0xF78);   // vmcnt(8): bufC's 4 loads done
        __builtin_amdgcn_s_barrier();
        MEMFENCE;
        compute(bufC); bufC = (bufC == 2) ? 0 : bufC + 1;
        MEMFENCE;
        __builtin_amdgcn_s_barrier();        // protect bufC before next overwrite
        MEMFENCE;
    }
    // kb = nk-2 (no more stages; 8 loads outstanding)
    __builtin_amdgcn_s_waitcnt(0xF74);       // vmcnt(4)
    __builtin_amdgcn_s_barrier();
    MEMFENCE;
    compute(bufC); bufC = (bufC == 2) ? 0 : bufC + 1;
    // kb = nk-1
    MEMFENCE;
    __builtin_amdgcn_s_waitcnt(0xF70);       // vmcnt(0)
    __builtin_amdgcn_s_barrier();
    MEMFENCE;
    compute(bufC);

    // epilogue: C/D layout col = lane&15, row = (lane>>4)*4 + reg
    const int col0 = bn * 128 + wn * 64 + lm;
    const int row0 = bm * 128 + wm * 64 + ((lane >> 4) << 2);

    const bool side = CAT && (bn >= 8);
    const float* bp = side ? bias1 : bias0;
    __bf16* Cout = side ? C1 : C0;

    float rowdot[16];
    if (HEAD) {
#pragma unroll
        for (int q = 0; q < 16; ++q) rowdot[q] = 0.0f;
    }

#pragma unroll
    for (int ni = 0; ni < 4; ++ni) {
        const int gn = col0 + ni * 16;
        const int gnl = CAT ? (gn & 1023) : gn;
        const float bv = bp[gnl];
        const float wv = HEAD ? wout[gn] : 0.0f;
#pragma unroll
        for (int mi = 0; mi < 4; ++mi) {
            const int gmb = row0 + mi * 16;
#pragma unroll
            for (int rr = 0; rr < 4; ++rr) {
                const int gm = gmb + rr;
                float v = gelu_exact(acc[mi][ni][rr] + bv);
                if (RES) v += (float)A[(size_t)gm * K + gn];
                if (HEAD) {
                    rowdot[mi * 4 + rr] += v * wv;
                } else {
                    Cout[(size_t)gm * 1024 + gnl] = (__bf16)v;
                }
            }
        }
    }

    if (HEAD) {
        // reduce across the 16 lanes (lm) of each row group
#pragma unroll
        for (int s = 1; s < 16; s <<= 1)
#pragma unroll
            for (int q = 0; q < 16; ++q) rowdot[q] += __shfl_xor(rowdot[q], s);
        if (lm == 0) {
            // per-(bn,wn) slab: wn=0 holds cols 0-63, wn=1 cols 64-127 of this
            // block -- they MUST NOT share a slot (round-3 bug: plain-store
            // collision dropped half the dot). 16 slabs, one writer per slot.
            float* dp = dotArr + (size_t)(bn * 2 + wn) * 32768 + row0;
#pragma unroll
            for (int q = 0; q < 16; ++q)
                dp[(q >> 2) * 16 + (q & 3)] = rowdot[q];
        }
    }
}

// ---------------------------------------------------------------------------
// finalize: sum 16 (bn,wn)-partials per row; block = (b,j), reduce over i
// ---------------------------------------------------------------------------
__global__ __launch_bounds__(128)
void finalize(const float* __restrict__ dot_e, const float* __restrict__ dot_f,
              const float* __restrict__ eb, const float* __restrict__ fb,
              const float* __restrict__ vec, float* __restrict__ out) {
    const int bj = blockIdx.x;          // bb*128 + jj
    const int bb = bj >> 7, jj = bj & 127;
    const int i = threadIdx.x;
    const int m = (i * 128 + jj) * 2 + bb;
    float e = eb[0], f = fb[0];
#pragma unroll
    for (int s = 0; s < 16; ++s) {
        e += dot_e[(size_t)s * 32768 + m];
        f += dot_f[(size_t)s * 32768 + m];
    }
    f *= (1.0f / 60.0f);
    float fx = f * vec[(size_t)m * 3 + 0];
    float fy = f * vec[(size_t)m * 3 + 1];
    float fz = f * vec[(size_t)m * 3 + 2];
#pragma unroll
    for (int off = 32; off > 0; off >>= 1) {
        e  += __shfl_down(e, off);
        fx += __shfl_down(fx, off);
        fy += __shfl_down(fy, off);
        fz += __shfl_down(fz, off);
    }
    __shared__ float red[2][4];
    const int wv = i >> 6, lane = i & 63;
    if (lane == 0) { red[wv][0] = e; red[wv][1] = fx; red[wv][2] = fy; red[wv][3] = fz; }
    __syncthreads();
    if (i == 0) {
        atomicAdd(&out[bb], (red[0][0] + red[1][0]) * (1.0f / 3600.0f));
        float* fo = out + 2 + bj * 3;
        fo[0] = red[0][1] + red[1][1];
        fo[1] = red[0][2] + red[1][2];
        fo[2] = red[0][3] + red[1][3];
    }
}

// ---------------------------------------------------------------------------
extern "C" void kernel_launch(void* const* d_in, const int* in_sizes, int n_in,
                              void* d_out, int out_size, void* d_ws, size_t ws_size,
                              hipStream_t stream) {
    const float* x     = (const float*)d_in[0];
    const float* dist  = (const float*)d_in[1];
    const float* vec   = (const float*)d_in[2];
    const float* rbfW  = (const float*)d_in[4];
    const float* rbf_b = (const float*)d_in[5];
    const float* eWin  = (const float*)d_in[6];
    const float* ebin  = (const float*)d_in[7];
    const float* eWh   = (const float*)d_in[8];
    const float* ebh   = (const float*)d_in[9];
    const float* eWout = (const float*)d_in[10];
    const float* ebout = (const float*)d_in[11];
    const float* fWin  = (const float*)d_in[12];
    const float* fbin  = (const float*)d_in[13];
    const float* fWh   = (const float*)d_in[14];
    const float* fbh   = (const float*)d_in[15];
    const float* fWout = (const float*)d_in[16];
    const float* fbout = (const float*)d_in[17];
    float* out = (float*)d_out;

    char* p = (char*)d_ws;
    __bf16* WinTcat = (__bf16*)p;                 // [2048][1536]
    __bf16* eWinT = WinTcat;          p += (size_t)1024 * 1536 * 2;
    __bf16* fWinT = (__bf16*)p;       p += (size_t)1024 * 1536 * 2;
    __bf16* eWhT[3];
    __bf16* fWhT[3];
    for (int l = 0; l < 3; ++l) { eWhT[l] = (__bf16*)p; p += (size_t)1024 * 1024 * 2; }
    for (int l = 0; l < 3; ++l) { fWhT[l] = (__bf16*)p; p += (size_t)1024 * 1024 * 2; }
    __bf16* rbfWb = (__bf16*)p;       p += 51200;
    float* dot_e = (float*)p;         p += (size_t)16 * 32768 * 4;   // per-(bn,wn) partials
    float* dot_f = (float*)p;         p += (size_t)16 * 32768 * 4;
    const size_t fixed = (size_t)(p - (char*)d_ws);

    int nchunk = 1;
    while (nchunk < 16 && fixed + (size_t)(32768 / nchunk) * 7168 > ws_size) nchunk <<= 1;
    const int CM = 32768 / nchunk;

    __bf16* feat = (__bf16*)p;                      // CM*1536 elems
    __bf16* hAlt = feat;                            // he1 / hf1 alias (CM*1024)
    __bf16* he0  = feat + (size_t)CM * 1536;
    __bf16* hf0  = he0 + (size_t)CM * 1024;

    zero_out<<<dim3(4), dim3(256), 0, stream>>>(out, 770);

    transpose_to_bf16<<<dim3(24, 16), dim3(256), 0, stream>>>(eWin, eWinT, 1536, 1024);
    transpose_to_bf16<<<dim3(24, 16), dim3(256), 0, stream>>>(fWin, fWinT, 1536, 1024);
    for (int l = 0; l < 3; ++l) {
        transpose_to_bf16<<<dim3(16, 16), dim3(256), 0, stream>>>(
            eWh + (size_t)l * 1048576, eWhT[l], 1024, 1024);
        transpose_to_bf16<<<dim3(16, 16), dim3(256), 0, stream>>>(
            fWh + (size_t)l * 1048576, fWhT[l], 1024, 1024);
    }
    f32_to_bf16<<<dim3(25), dim3(256), 0, stream>>>(rbfW, rbfWb, 25600);

    for (int c = 0; c < nchunk; ++c) {
        const int m0 = c * CM;
        build_feat<<<dim3(CM / 16), dim3(256), 0, stream>>>(x, dist, rbfWb, rbf_b, feat, m0);

        const dim3 blk(256);
        // layer-0 merged: feat @ [eWin|fWin] -> he0, hf0
        gemm_fused<false, true, false><<<dim3((CM / 128) * 16), blk, 0, stream>>>(
            feat, WinTcat, ebin, fbin, he0, hf0, nullptr, nullptr, 1536);
        // e-branch
        gemm_fused<true, false, false><<<dim3((CM / 128) * 8), blk, 0, stream>>>(
            he0, eWhT[0], ebh + 0, nullptr, hAlt, nullptr, nullptr, nullptr, 1024);
        gemm_fused<true, false, false><<<dim3((CM / 128) * 8), blk, 0, stream>>>(
            hAlt, eWhT[1], ebh + 1024, nullptr, he0, nullptr, nullptr, nullptr, 1024);
        gemm_fused<true, false, true><<<dim3((CM / 128) * 8), blk, 0, stream>>>(
            he0, eWhT[2], ebh + 2048, nullptr, nullptr, nullptr, eWout, dot_e + m0, 1024);
        // f-branch
        gemm_fused<true, false, false><<<dim3((CM / 128) * 8), blk, 0, stream>>>(
            hf0, fWhT[0], fbh + 0, nullptr, hAlt, nullptr, nullptr, nullptr, 1024);
        gemm_fused<true, false, false><<<dim3((CM / 128) * 8), blk, 0, stream>>>(
            hAlt, fWhT[1], fbh + 1024, nullptr, hf0, nullptr, nullptr, nullptr, 1024);
        gemm_fused<true, false, true><<<dim3((CM / 128) * 8), blk, 0, stream>>>(
            hf0, fWhT[2], fbh + 2048, nullptr, nullptr, nullptr, fWout, dot_f + m0, 1024);
    }

    finalize<<<dim3(256), dim3(128), 0, stream>>>(dot_e, dot_f, ebout, fbout, vec, out);
}

// Round 5
// 1351.333 us; speedup vs baseline: 1.3854x; 1.3854x over previous
//
#include <hip/hip_runtime.h>
#include <stdint.h>

typedef __bf16 bf16x8 __attribute__((ext_vector_type(8)));
typedef __bf16 bf16x4 __attribute__((ext_vector_type(4)));
typedef float  f32x4  __attribute__((ext_vector_type(4)));
typedef unsigned int u32;

__device__ __forceinline__ void gl_lds16(const void* gptr, void* lptr) {
    __builtin_amdgcn_global_load_lds(
        (const __attribute__((address_space(1))) u32*)gptr,
        (__attribute__((address_space(3))) u32*)lptr,
        16, 0, 0);
}

__device__ __forceinline__ float gelu_exact(float x) {
    return 0.5f * x * (1.0f + erff(x * 0.70710678118654752f));
}

#define MEMFENCE __asm__ __volatile__("" ::: "memory")

__global__ void zero_out(float* __restrict__ o, int n) {
    int i = blockIdx.x * 256 + threadIdx.x;
    if (i < n) o[i] = 0.0f;
}

// ---------------------------------------------------------------------------
// fp32 [K][N] -> bf16 transposed [N][K]
// ---------------------------------------------------------------------------
__global__ __launch_bounds__(256)
void transpose_to_bf16(const float* __restrict__ src, __bf16* __restrict__ dst,
                       int K, int Ncols) {
    __shared__ float tile[64][65];
    const int bk = blockIdx.x * 64;
    const int bn = blockIdx.y * 64;
    const int tid = threadIdx.x;
    const int tr = tid >> 4;
    const int tc = (tid & 15) * 4;
#pragma unroll
    for (int p = 0; p < 4; ++p) {
        const int r = tr + p * 16;
        float4 v = *(const float4*)&src[(size_t)(bk + r) * Ncols + bn + tc];
        tile[r][tc] = v.x; tile[r][tc + 1] = v.y;
        tile[r][tc + 2] = v.z; tile[r][tc + 3] = v.w;
    }
    __syncthreads();
#pragma unroll
    for (int p = 0; p < 4; ++p) {
        const int rn = tr + p * 16;
        bf16x4 o;
        o[0] = (__bf16)tile[tc + 0][rn];
        o[1] = (__bf16)tile[tc + 1][rn];
        o[2] = (__bf16)tile[tc + 2][rn];
        o[3] = (__bf16)tile[tc + 3][rn];
        *(bf16x4*)&dst[(size_t)(bn + rn) * K + bk + tc] = o;
    }
}

__global__ void f32_to_bf16(const float* __restrict__ s, __bf16* __restrict__ d, int n) {
    int idx = blockIdx.x * 256 + threadIdx.x;
    if (idx * 4 < n) {
        float4 v = *(const float4*)(s + idx * 4);
        bf16x4 o;
        o[0] = (__bf16)v.x; o[1] = (__bf16)v.y; o[2] = (__bf16)v.z; o[3] = (__bf16)v.w;
        *(bf16x4*)(d + idx * 4) = o;
    }
}

// M1 bf16 [128][512]: rows 0..49 = rbf_W, row 50 = rbf_b, rows 51..127 = 0
__global__ void build_M1(const float* __restrict__ rbfW, const float* __restrict__ rbf_b,
                         __bf16* __restrict__ M1) {
    int t = blockIdx.x * 256 + threadIdx.x;        // 32768 threads
    int r = t >> 8;
    int c = (t & 255) * 2;
    float v0 = 0.f, v1 = 0.f;
    if (r < 50)       { v0 = rbfW[r * 512 + c]; v1 = rbfW[r * 512 + c + 1]; }
    else if (r == 50) { v0 = rbf_b[c];          v1 = rbf_b[c + 1]; }
    M1[r * 512 + c] = (__bf16)v0;
    M1[r * 512 + c + 1] = (__bf16)v1;
}

// G bf16 [32768][64]: cols 0..49 = exp(coeff*(dist-k*sp)^2), col 50 = 1, rest 0
__global__ __launch_bounds__(256)
void build_G(const float* __restrict__ dist, __bf16* __restrict__ G) {
    const int t = threadIdx.x;
    const int row = blockIdx.x * 32 + (t >> 3);
    const int c0 = (t & 7) * 8;
    const float sp = 12.0f / 49.0f;
    const float coeff = -0.5f / (sp * sp);
    const float d = dist[row];
    bf16x8 v;
#pragma unroll
    for (int q = 0; q < 8; ++q) {
        const int k = c0 + q;
        float val;
        if (k < 50)       { float tt = d - (float)k * sp; val = __expf(coeff * tt * tt); }
        else if (k == 50) val = 1.0f;
        else              val = 0.0f;
        v[q] = (__bf16)val;
    }
    *(bf16x8*)(G + (size_t)row * 64 + c0) = v;
}

// ---------------------------------------------------------------------------
// Generic 128x128-tile MFMA GEMM, 3-stage LDS pipeline, FULLY UNROLLED K-loop
// (constant buffer indices -> no v_cndmask rotation chains).
// MODE 0 HID : C0 = gelu(acc+bias0) + A        (K==N==1024)
// MODE 1 HEAD: rowdot(gelu(acc+bias0)+A, wout) -> dotArr[(bn*2+wn)*32768+m]
// MODE 2 L0  : dual-out gelu(acc + bias + P0[p0row] + P1[p1row]) -> C0/C1
// MODE 3 RAWF32 : Cf = acc
// MODE 4 RAWBF16: C0 = (bf16)acc
// ---------------------------------------------------------------------------
template <int NK, int NBN, int MODE>
__global__ __launch_bounds__(256)
void gemm_k(const __bf16* __restrict__ A, const __bf16* __restrict__ Bt,
            int lda, int ldb, int ldc,
            const float* __restrict__ bias0, const float* __restrict__ bias1,
            __bf16* __restrict__ C0, __bf16* __restrict__ C1,
            float* __restrict__ Cf,
            const float* __restrict__ P0, const float* __restrict__ P1,
            const float* __restrict__ wout, float* __restrict__ dotArr) {
    constexpr int NBS = (NBN == 16) ? 4 : (NBN == 8) ? 3 : 0;
    __shared__ __align__(16) __bf16 As[3][128 * 32];
    __shared__ __align__(16) __bf16 Bs[3][128 * 32];

    const int tid = threadIdx.x;
    const int flat = blockIdx.x;
    const int bn = flat & (NBN - 1);
    const int bm = flat >> NBS;
    const int w = tid >> 6;
    const int lane = tid & 63;

    const int r0 = tid >> 2;
    const int s0 = tid & 3;
    const char* gA0 = (const char*)A + (size_t)(bm * 128 + r0) * lda + s0 * 16;
    const char* gA1 = gA0 + (size_t)64 * lda;
    const char* gB0 = (const char*)Bt + (size_t)(bn * 128 + r0) * ldb + s0 * 16;
    const char* gB1 = gB0 + (size_t)64 * ldb;

    char* lA0 = (char*)&As[0][0] + w * 1024;
    char* lA1 = (char*)&As[1][0] + w * 1024;
    char* lA2 = (char*)&As[2][0] + w * 1024;
    char* lB0 = (char*)&Bs[0][0] + w * 1024;
    char* lB1 = (char*)&Bs[1][0] + w * 1024;
    char* lB2 = (char*)&Bs[2][0] + w * 1024;

    const int wm = (w >> 1) & 1;
    const int wn = w & 1;
    const int lm = lane & 15;
    const int ko = (lane >> 4) << 3;
    const int fo = (wm * 64 + lm) * 32 + ko;
    const int go = (wn * 64 + lm) * 32 + ko;
    const __bf16* pA0 = &As[0][0] + fo;
    const __bf16* pA1 = &As[1][0] + fo;
    const __bf16* pA2 = &As[2][0] + fo;
    const __bf16* pB0 = &Bs[0][0] + go;
    const __bf16* pB1 = &Bs[1][0] + go;
    const __bf16* pB2 = &Bs[2][0] + go;

    f32x4 acc[4][4];
    const f32x4 zero = {0.0f, 0.0f, 0.0f, 0.0f};
#pragma unroll
    for (int i = 0; i < 4; ++i)
#pragma unroll
        for (int j = 0; j < 4; ++j) acc[i][j] = zero;

    auto stage = [&](int buf) {   // buf is compile-time constant at every call
        char* la = (buf == 0) ? lA0 : (buf == 1) ? lA1 : lA2;
        char* lb = (buf == 0) ? lB0 : (buf == 1) ? lB1 : lB2;
        gl_lds16(gA0, la); gl_lds16(gA1, la + 4096);
        gl_lds16(gB0, lb); gl_lds16(gB1, lb + 4096);
        gA0 += 64; gA1 += 64; gB0 += 64; gB1 += 64;
    };
    auto compute = [&](int buf) {
        const __bf16* pa = (buf == 0) ? pA0 : (buf == 1) ? pA1 : pA2;
        const __bf16* pb = (buf == 0) ? pB0 : (buf == 1) ? pB1 : pB2;
        bf16x8 af[4], bfg[4];
#pragma unroll
        for (int i = 0; i < 4; ++i) {
            af[i]  = *(const bf16x8*)(pa + i * 512);
            bfg[i] = *(const bf16x8*)(pb + i * 512);
        }
#pragma unroll
        for (int mi = 0; mi < 4; ++mi)
#pragma unroll
            for (int ni = 0; ni < 4; ++ni)
                acc[mi][ni] = __builtin_amdgcn_mfma_f32_16x16x32_bf16(
                    af[mi], bfg[ni], acc[mi][ni], 0, 0, 0);
    };

    stage(0);
    stage(1);
    if constexpr (NK > 2) {
#pragma unroll
        for (int kb = 0; kb < NK - 2; ++kb) {
            stage((kb + 2) % 3);
            MEMFENCE;
            __builtin_amdgcn_s_waitcnt(0xF78);   // vmcnt(8): oldest buffer landed
            __builtin_amdgcn_s_barrier();
            MEMFENCE;
            compute(kb % 3);
            MEMFENCE;
            __builtin_amdgcn_s_barrier();        // protect buffer before overwrite
            MEMFENCE;
        }
    }
    MEMFENCE;
    __builtin_amdgcn_s_waitcnt(0xF74);           // vmcnt(4)
    __builtin_amdgcn_s_barrier();
    MEMFENCE;
    compute((NK - 2) % 3);
    MEMFENCE;
    __builtin_amdgcn_s_waitcnt(0xF70);           // vmcnt(0)
    __builtin_amdgcn_s_barrier();
    MEMFENCE;
    compute((NK - 1) % 3);

    // epilogue: C/D layout col = lane&15, row = (lane>>4)*4 + reg
    const int col0 = bn * 128 + wn * 64 + lm;
    const int row0 = bm * 128 + wm * 64 + ((lane >> 4) << 2);
    const int ldaE = lda >> 1;

    float rowdot[16];
    if constexpr (MODE == 1) {
#pragma unroll
        for (int q = 0; q < 16; ++q) rowdot[q] = 0.0f;
    }

    const bool side = (MODE == 2) && (bn >= 8);
    const float* bp = (MODE == 2) ? (side ? bias1 : bias0) : bias0;
    __bf16* Cout = (MODE == 2) ? (side ? C1 : C0) : C0;

#pragma unroll
    for (int ni = 0; ni < 4; ++ni) {
        const int gn = col0 + ni * 16;
        const int gnl = (MODE == 2) ? (gn & 1023) : gn;
        float bv = 0.0f;
        if constexpr (MODE <= 2) bv = bp[gnl];
        float wv = 0.0f;
        if constexpr (MODE == 1) wv = wout[gn];
#pragma unroll
        for (int mi = 0; mi < 4; ++mi) {
            const int gmb = row0 + mi * 16;
#pragma unroll
            for (int rr = 0; rr < 4; ++rr) {
                const int gm = gmb + rr;
                const float a = acc[mi][ni][rr];
                if constexpr (MODE == 0) {
                    float v = gelu_exact(a + bv) + (float)A[(size_t)gm * ldaE + gn];
                    Cout[(size_t)gm * ldc + gn] = (__bf16)v;
                } else if constexpr (MODE == 1) {
                    float v = gelu_exact(a + bv) + (float)A[(size_t)gm * ldaE + gn];
                    rowdot[mi * 4 + rr] += v * wv;
                } else if constexpr (MODE == 2) {
                    const int p0row = ((gm >> 8) << 1) | (gm & 1);
                    const int p1row = gm & 255;
                    float v = a + bv + P0[(size_t)p0row * 2048 + gn]
                                     + P1[(size_t)p1row * 2048 + gn];
                    Cout[(size_t)gm * ldc + gnl] = (__bf16)gelu_exact(v);
                } else if constexpr (MODE == 3) {
                    Cf[(size_t)gm * ldc + gn] = a;
                } else {
                    Cout[(size_t)gm * ldc + gn] = (__bf16)a;
                }
            }
        }
    }

    if constexpr (MODE == 1) {
#pragma unroll
        for (int s = 1; s < 16; s <<= 1)
#pragma unroll
            for (int q = 0; q < 16; ++q) rowdot[q] += __shfl_xor(rowdot[q], s);
        if (lm == 0) {
            float* dp = dotArr + (size_t)(bn * 2 + wn) * 32768 + row0;
#pragma unroll
            for (int q = 0; q < 16; ++q)
                dp[(q >> 2) * 16 + (q & 3)] = rowdot[q];
        }
    }
}

// ---------------------------------------------------------------------------
// finalize: sum 16 (bn,wn)-partials per row; block = (b,j), reduce over i
// ---------------------------------------------------------------------------
__global__ __launch_bounds__(128)
void finalize(const float* __restrict__ dot_e, const float* __restrict__ dot_f,
              const float* __restrict__ eb, const float* __restrict__ fb,
              const float* __restrict__ vec, float* __restrict__ out) {
    const int bj = blockIdx.x;
    const int bb = bj >> 7, jj = bj & 127;
    const int i = threadIdx.x;
    const int m = (i * 128 + jj) * 2 + bb;
    float e = eb[0], f = fb[0];
#pragma unroll
    for (int s = 0; s < 16; ++s) {
        e += dot_e[(size_t)s * 32768 + m];
        f += dot_f[(size_t)s * 32768 + m];
    }
    f *= (1.0f / 60.0f);
    float fx = f * vec[(size_t)m * 3 + 0];
    float fy = f * vec[(size_t)m * 3 + 1];
    float fz = f * vec[(size_t)m * 3 + 2];
#pragma unroll
    for (int off = 32; off > 0; off >>= 1) {
        e  += __shfl_down(e, off);
        fx += __shfl_down(fx, off);
        fy += __shfl_down(fy, off);
        fz += __shfl_down(fz, off);
    }
    __shared__ float red[2][4];
    const int wv = i >> 6, lane = i & 63;
    if (lane == 0) { red[wv][0] = e; red[wv][1] = fx; red[wv][2] = fy; red[wv][3] = fz; }
    __syncthreads();
    if (i == 0) {
        atomicAdd(&out[bb], (red[0][0] + red[1][0]) * (1.0f / 3600.0f));
        float* fo = out + 2 + bj * 3;
        fo[0] = red[0][1] + red[1][1];
        fo[1] = red[0][2] + red[1][2];
        fo[2] = red[0][3] + red[1][3];
    }
}

// ---------------------------------------------------------------------------
extern "C" void kernel_launch(void* const* d_in, const int* in_sizes, int n_in,
                              void* d_out, int out_size, void* d_ws, size_t ws_size,
                              hipStream_t stream) {
    const float* x     = (const float*)d_in[0];
    const float* dist  = (const float*)d_in[1];
    const float* vec   = (const float*)d_in[2];
    const float* rbfW  = (const float*)d_in[4];
    const float* rbf_b = (const float*)d_in[5];
    const float* eWin  = (const float*)d_in[6];
    const float* ebin  = (const float*)d_in[7];
    const float* eWh   = (const float*)d_in[8];
    const float* ebh   = (const float*)d_in[9];
    const float* eWout = (const float*)d_in[10];
    const float* ebout = (const float*)d_in[11];
    const float* fWin  = (const float*)d_in[12];
    const float* fbin  = (const float*)d_in[13];
    const float* fWh   = (const float*)d_in[14];
    const float* fbh   = (const float*)d_in[15];
    const float* fWout = (const float*)d_in[16];
    const float* fbout = (const float*)d_in[17];
    float* out = (float*)d_out;

    // workspace carve (~227 MB; ws proven >= ~263 MB in rounds 2/4)
    char* p = (char*)d_ws;
    __bf16* WinTcat = (__bf16*)p;                 // [2048][1536] = [eWin^T; fWin^T]
    __bf16* eWinT = WinTcat;          p += (size_t)1024 * 1536 * 2;
    __bf16* fWinT = (__bf16*)p;       p += (size_t)1024 * 1536 * 2;
    __bf16* eWhT[3];
    __bf16* fWhT[3];
    for (int l = 0; l < 3; ++l) { eWhT[l] = (__bf16*)p; p += (size_t)1024 * 1024 * 2; }
    for (int l = 0; l < 3; ++l) { fWhT[l] = (__bf16*)p; p += (size_t)1024 * 1024 * 2; }
    __bf16* xb  = (__bf16*)p;         p += (size_t)256 * 512 * 2;     // x as bf16
    __bf16* M1  = (__bf16*)p;         p += (size_t)128 * 512 * 2;     // rbfW|rbf_b|0
    __bf16* WgT = (__bf16*)p;         p += (size_t)2048 * 128 * 2;    // Wg^T padded
    __bf16* G   = (__bf16*)p;         p += (size_t)32768 * 64 * 2;    // gaussians|1|0
    float* P0   = (float*)p;          p += (size_t)256 * 2048 * 4;    // x@Win_xi
    float* P1   = (float*)p;          p += (size_t)256 * 2048 * 4;    // x@Win_xj
    float* dot_e = (float*)p;         p += (size_t)16 * 32768 * 4;
    float* dot_f = (float*)p;         p += (size_t)16 * 32768 * 4;
    __bf16* he0  = (__bf16*)p;        p += (size_t)32768 * 1024 * 2;
    __bf16* hf0  = (__bf16*)p;        p += (size_t)32768 * 1024 * 2;
    __bf16* hAlt = (__bf16*)p;        p += (size_t)32768 * 1024 * 2;

    zero_out<<<dim3(4), dim3(256), 0, stream>>>(out, 770);

    // weight prep
    transpose_to_bf16<<<dim3(24, 16), dim3(256), 0, stream>>>(eWin, eWinT, 1536, 1024);
    transpose_to_bf16<<<dim3(24, 16), dim3(256), 0, stream>>>(fWin, fWinT, 1536, 1024);
    for (int l = 0; l < 3; ++l) {
        transpose_to_bf16<<<dim3(16, 16), dim3(256), 0, stream>>>(
            eWh + (size_t)l * 1048576, eWhT[l], 1024, 1024);
        transpose_to_bf16<<<dim3(16, 16), dim3(256), 0, stream>>>(
            fWh + (size_t)l * 1048576, fWhT[l], 1024, 1024);
    }
    f32_to_bf16<<<dim3(128), dim3(256), 0, stream>>>(x, xb, 131072);
    build_M1<<<dim3(128), dim3(256), 0, stream>>>(rbfW, rbf_b, M1);
    build_G<<<dim3(1024), dim3(256), 0, stream>>>(dist, G);

    const dim3 blk(256);
    // P0/P1: x(256x512) @ Win rows [0:512) / [512:1024)  -> f32 (256x2048)
    gemm_k<16, 16, 3><<<dim3(32), blk, 0, stream>>>(
        xb, WinTcat, 1024, 3072, 2048, nullptr, nullptr,
        nullptr, nullptr, P0, nullptr, nullptr, nullptr, nullptr);
    gemm_k<16, 16, 3><<<dim3(32), blk, 0, stream>>>(
        xb, WinTcat + 512, 1024, 3072, 2048, nullptr, nullptr,
        nullptr, nullptr, P1, nullptr, nullptr, nullptr, nullptr);
    // WgT(2048x128) = WinTcat[:,1024:1536] @ M1^T  (bf16 raw)
    gemm_k<16, 1, 4><<<dim3(16), blk, 0, stream>>>(
        WinTcat + 1024, M1, 3072, 1024, 128, nullptr, nullptr,
        WgT, nullptr, nullptr, nullptr, nullptr, nullptr, nullptr);
    // layer 0: he0|hf0 = gelu(G @ Wg + bias + P0[i,b] + P1[j,b])
    gemm_k<2, 16, 2><<<dim3(4096), blk, 0, stream>>>(
        G, WgT, 128, 256, 1024, ebin, fbin,
        he0, hf0, nullptr, P0, P1, nullptr, nullptr);

    // e-branch: 2 residual layers + fused head
    gemm_k<32, 8, 0><<<dim3(2048), blk, 0, stream>>>(
        he0, eWhT[0], 2048, 2048, 1024, ebh + 0, nullptr,
        hAlt, nullptr, nullptr, nullptr, nullptr, nullptr, nullptr);
    gemm_k<32, 8, 0><<<dim3(2048), blk, 0, stream>>>(
        hAlt, eWhT[1], 2048, 2048, 1024, ebh + 1024, nullptr,
        he0, nullptr, nullptr, nullptr, nullptr, nullptr, nullptr);
    gemm_k<32, 8, 1><<<dim3(2048), blk, 0, stream>>>(
        he0, eWhT[2], 2048, 2048, 1024, ebh + 2048, nullptr,
        nullptr, nullptr, nullptr, nullptr, nullptr, eWout, dot_e);
    // f-branch
    gemm_k<32, 8, 0><<<dim3(2048), blk, 0, stream>>>(
        hf0, fWhT[0], 2048, 2048, 1024, fbh + 0, nullptr,
        hAlt, nullptr, nullptr, nullptr, nullptr, nullptr, nullptr);
    gemm_k<32, 8, 0><<<dim3(2048), blk, 0, stream>>>(
        hAlt, fWhT[1], 2048, 2048, 1024, fbh + 1024, nullptr,
        hf0, nullptr, nullptr, nullptr, nullptr, nullptr, nullptr);
    gemm_k<32, 8, 1><<<dim3(2048), blk, 0, stream>>>(
        hf0, fWhT[2], 2048, 2048, 1024, fbh + 2048, nullptr,
        nullptr, nullptr, nullptr, nullptr, nullptr, fWout, dot_f);

    finalize<<<dim3(256), dim3(128), 0, stream>>>(dot_e, dot_f, ebout, fbout, vec, out);
}

// Round 6
// 1276.398 us; speedup vs baseline: 1.4668x; 1.0587x over previous
//
#include <hip/hip_runtime.h>
#include <stdint.h>

typedef __bf16 bf16x8 __attribute__((ext_vector_type(8)));
typedef __bf16 bf16x4 __attribute__((ext_vector_type(4)));
typedef float  f32x4  __attribute__((ext_vector_type(4)));
typedef unsigned int u32;

__device__ __forceinline__ void gl_lds16(const void* gptr, void* lptr) {
    __builtin_amdgcn_global_load_lds(
        (const __attribute__((address_space(1))) u32*)gptr,
        (__attribute__((address_space(3))) u32*)lptr,
        16, 0, 0);
}

__device__ __forceinline__ float gelu_exact(float x) {
    return 0.5f * x * (1.0f + erff(x * 0.70710678118654752f));
}

#define MEMFENCE __asm__ __volatile__("" ::: "memory")

__global__ void zero_out(float* __restrict__ o, int n) {
    int i = blockIdx.x * 256 + threadIdx.x;
    if (i < n) o[i] = 0.0f;
}

// ---------------------------------------------------------------------------
// fp32 [K][N] -> bf16 transposed [N][K]; z selects (branch,l) pair
// ---------------------------------------------------------------------------
__global__ __launch_bounds__(256)
void transpose_multi(const float* __restrict__ src0, const float* __restrict__ src1,
                     __bf16* __restrict__ dst0, __bf16* __restrict__ dst1,
                     int K, int Ncols, int perBranch) {
    const int z = blockIdx.z;
    const int branch = z / perBranch;
    const int l = z - branch * perBranch;
    const size_t elems = (size_t)K * Ncols;
    const float* src = (branch ? src1 : src0) + (size_t)l * elems;
    __bf16* dst = (branch ? dst1 : dst0) + (size_t)l * elems;

    __shared__ float tile[64][65];
    const int bk = blockIdx.x * 64;
    const int bn = blockIdx.y * 64;
    const int tid = threadIdx.x;
    const int tr = tid >> 4;
    const int tc = (tid & 15) * 4;
#pragma unroll
    for (int p = 0; p < 4; ++p) {
        const int r = tr + p * 16;
        float4 v = *(const float4*)&src[(size_t)(bk + r) * Ncols + bn + tc];
        tile[r][tc] = v.x; tile[r][tc + 1] = v.y;
        tile[r][tc + 2] = v.z; tile[r][tc + 3] = v.w;
    }
    __syncthreads();
#pragma unroll
    for (int p = 0; p < 4; ++p) {
        const int rn = tr + p * 16;
        bf16x4 o;
        o[0] = (__bf16)tile[tc + 0][rn];
        o[1] = (__bf16)tile[tc + 1][rn];
        o[2] = (__bf16)tile[tc + 2][rn];
        o[3] = (__bf16)tile[tc + 3][rn];
        *(bf16x4*)&dst[(size_t)(bn + rn) * K + bk + tc] = o;
    }
}

__global__ void f32_to_bf16(const float* __restrict__ s, __bf16* __restrict__ d, int n) {
    int idx = blockIdx.x * 256 + threadIdx.x;
    if (idx * 4 < n) {
        float4 v = *(const float4*)(s + idx * 4);
        bf16x4 o;
        o[0] = (__bf16)v.x; o[1] = (__bf16)v.y; o[2] = (__bf16)v.z; o[3] = (__bf16)v.w;
        *(bf16x4*)(d + idx * 4) = o;
    }
}

// M1 bf16 [128][512]: rows 0..49 = rbf_W, row 50 = rbf_b, rows 51..127 = 0
__global__ void build_M1(const float* __restrict__ rbfW, const float* __restrict__ rbf_b,
                         __bf16* __restrict__ M1) {
    int t = blockIdx.x * 256 + threadIdx.x;
    int r = t >> 8;
    int c = (t & 255) * 2;
    float v0 = 0.f, v1 = 0.f;
    if (r < 50)       { v0 = rbfW[r * 512 + c]; v1 = rbfW[r * 512 + c + 1]; }
    else if (r == 50) { v0 = rbf_b[c];          v1 = rbf_b[c + 1]; }
    M1[r * 512 + c] = (__bf16)v0;
    M1[r * 512 + c + 1] = (__bf16)v1;
}

// G bf16 [32768][64]: cols 0..49 = exp(coeff*(dist-k*sp)^2), col 50 = 1, rest 0
__global__ __launch_bounds__(256)
void build_G(const float* __restrict__ dist, __bf16* __restrict__ G) {
    const int t = threadIdx.x;
    const int row = blockIdx.x * 32 + (t >> 3);
    const int c0 = (t & 7) * 8;
    const float sp = 12.0f / 49.0f;
    const float coeff = -0.5f / (sp * sp);
    const float d = dist[row];
    bf16x8 v;
#pragma unroll
    for (int q = 0; q < 8; ++q) {
        const int k = c0 + q;
        float val;
        if (k < 50)       { float tt = d - (float)k * sp; val = __expf(coeff * tt * tt); }
        else if (k == 50) val = 1.0f;
        else              val = 0.0f;
        v[q] = (__bf16)val;
    }
    *(bf16x8*)(G + (size_t)row * 64 + c0) = v;
}

// ---------------------------------------------------------------------------
// 128x128-tile MFMA GEMM. 3-stage LDS pipeline, ONE barrier per K-step:
//   [wait vmcnt(4); s_barrier; compute(kb%3); stage((kb+2)%3)]
// Partial unroll in groups of 3 -> constant buffer indices, small code.
// DUAL: grid doubled, high half = f-branch (A1/B1/bias1/...).
// MODE 0 HID : C = gelu(acc+bias)+A
// MODE 1 HEAD: rowdot(gelu(acc+bias)+A, wout) -> dot[(bn*2+wn)*32768+m]
// MODE 2 L0  : gelu(acc + bias + P0 + P1) -> he0/hf0 (side = bn>=8)
// MODE 3 RAWF32 : Cf = acc
// MODE 4 RAWBF16: C0 = (bf16)acc
// ---------------------------------------------------------------------------
template <int NK, int NBN, int MODE, bool DUAL>
__global__ __launch_bounds__(256, 3)
void gemm_k(const __bf16* __restrict__ A0, const __bf16* __restrict__ A1,
            const __bf16* __restrict__ B0, const __bf16* __restrict__ B1,
            int lda, int ldb, int ldc,
            const float* __restrict__ bias0, const float* __restrict__ bias1,
            __bf16* __restrict__ C0, __bf16* __restrict__ C1,
            float* __restrict__ Cf0, float* __restrict__ Cf1,
            const float* __restrict__ P0, const float* __restrict__ P1,
            const float* __restrict__ wout0, const float* __restrict__ wout1,
            float* __restrict__ dot0, float* __restrict__ dot1) {
    constexpr int NBS = (NBN == 16) ? 4 : (NBN == 8) ? 3 : 0;
    __shared__ __align__(16) __bf16 As[3][128 * 32];
    __shared__ __align__(16) __bf16 Bs[3][128 * 32];

    const int tid = threadIdx.x;
    int f2 = blockIdx.x;
    int branch = 0;
    if constexpr (DUAL) {
        const int half = gridDim.x >> 1;
        branch = (f2 >= half);
        if (branch) f2 -= half;
    }
    const int bn = f2 & (NBN - 1);
    const int bm = f2 >> NBS;
    const int w = tid >> 6;
    const int lane = tid & 63;

    const __bf16* Ab = (DUAL && branch) ? A1 : A0;
    const __bf16* Bb = (DUAL && branch) ? B1 : B0;

    const int r0 = tid >> 2;
    const int s0 = tid & 3;
    const char* gA0 = (const char*)Ab + (size_t)(bm * 128 + r0) * lda + s0 * 16;
    const char* gA1 = gA0 + (size_t)64 * lda;
    const char* gB0 = (const char*)Bb + (size_t)(bn * 128 + r0) * ldb + s0 * 16;
    const char* gB1 = gB0 + (size_t)64 * ldb;

    char* lA0 = (char*)&As[0][0] + w * 1024;
    char* lA1 = (char*)&As[1][0] + w * 1024;
    char* lA2 = (char*)&As[2][0] + w * 1024;
    char* lB0 = (char*)&Bs[0][0] + w * 1024;
    char* lB1 = (char*)&Bs[1][0] + w * 1024;
    char* lB2 = (char*)&Bs[2][0] + w * 1024;

    const int wm = (w >> 1) & 1;
    const int wn = w & 1;
    const int lm = lane & 15;
    const int ko = (lane >> 4) << 3;
    const int fo = (wm * 64 + lm) * 32 + ko;
    const int go = (wn * 64 + lm) * 32 + ko;
    const __bf16* pA0 = &As[0][0] + fo;
    const __bf16* pA1 = &As[1][0] + fo;
    const __bf16* pA2 = &As[2][0] + fo;
    const __bf16* pB0 = &Bs[0][0] + go;
    const __bf16* pB1 = &Bs[1][0] + go;
    const __bf16* pB2 = &Bs[2][0] + go;

    f32x4 acc[4][4];
    const f32x4 zero = {0.0f, 0.0f, 0.0f, 0.0f};
#pragma unroll
    for (int i = 0; i < 4; ++i)
#pragma unroll
        for (int j = 0; j < 4; ++j) acc[i][j] = zero;

    auto stage = [&](int buf) {   // buf literal at every call site
        char* la = (buf == 0) ? lA0 : (buf == 1) ? lA1 : lA2;
        char* lb = (buf == 0) ? lB0 : (buf == 1) ? lB1 : lB2;
        gl_lds16(gA0, la); gl_lds16(gA1, la + 4096);
        gl_lds16(gB0, lb); gl_lds16(gB1, lb + 4096);
        gA0 += 64; gA1 += 64; gB0 += 64; gB1 += 64;
    };
    auto compute = [&](int buf) {
        const __bf16* pa = (buf == 0) ? pA0 : (buf == 1) ? pA1 : pA2;
        const __bf16* pb = (buf == 0) ? pB0 : (buf == 1) ? pB1 : pB2;
        bf16x8 af[4], bfg[4];
#pragma unroll
        for (int i = 0; i < 4; ++i) {
            af[i]  = *(const bf16x8*)(pa + i * 512);
            bfg[i] = *(const bf16x8*)(pb + i * 512);
        }
#pragma unroll
        for (int mi = 0; mi < 4; ++mi)
#pragma unroll
            for (int ni = 0; ni < 4; ++ni)
                acc[mi][ni] = __builtin_amdgcn_mfma_f32_16x16x32_bf16(
                    af[mi], bfg[ni], acc[mi][ni], 0, 0, 0);
    };
    auto iterstep = [&](int cbuf, int sbuf) {
        MEMFENCE;
        __builtin_amdgcn_s_waitcnt(0xF74);   // vmcnt(4): cbuf's 4 loads landed
        __builtin_amdgcn_s_barrier();        // all waves' cbuf loads landed;
        MEMFENCE;                            // also fences last iter's readers
        compute(cbuf);
        MEMFENCE;
        stage(sbuf);                         // overwrites buffer computed last
        MEMFENCE;                            // iter -- barrier above separates
    };

    stage(0);
    stage(1);
    constexpr int NIT = NK - 2;
    constexpr int NG = NIT / 3;
    constexpr int NR = NIT % 3;
    for (int g = 0; g < NG; ++g) {           // runtime loop, constant indices
        iterstep(0, 2);
        iterstep(1, 0);
        iterstep(2, 1);
    }
    if constexpr (NR >= 1) iterstep(0, 2);
    if constexpr (NR >= 2) iterstep(1, 0);
    // tails (no more stages)
    MEMFENCE;
    __builtin_amdgcn_s_waitcnt(0xF74);       // vmcnt(4)
    __builtin_amdgcn_s_barrier();
    MEMFENCE;
    compute((NK - 2) % 3);
    MEMFENCE;
    __builtin_amdgcn_s_waitcnt(0xF70);       // vmcnt(0)
    __builtin_amdgcn_s_barrier();
    MEMFENCE;
    compute((NK - 1) % 3);

    // epilogue: C/D layout col = lane&15, row = (lane>>4)*4 + reg
    const int col0 = bn * 128 + wn * 64 + lm;
    const int row0 = bm * 128 + wm * 64 + ((lane >> 4) << 2);
    const int ldaE = lda >> 1;

    float rowdot[16];
    if constexpr (MODE == 1) {
#pragma unroll
        for (int q = 0; q < 16; ++q) rowdot[q] = 0.0f;
    }

    const bool side = (MODE == 2) && (bn >= 8);
    const float* bp = (MODE == 2) ? (side ? bias1 : bias0)
                                  : ((DUAL && branch) ? bias1 : bias0);
    __bf16* Cout = (MODE == 2) ? (side ? C1 : C0)
                               : ((DUAL && branch) ? C1 : C0);
    const float* woutb = (MODE == 1) ? (branch ? wout1 : wout0) : nullptr;

#pragma unroll
    for (int ni = 0; ni < 4; ++ni) {
        const int gn = col0 + ni * 16;
        const int gnl = (MODE == 2) ? (gn & 1023) : gn;
        float bv = 0.0f;
        if constexpr (MODE <= 2) bv = bp[gnl];
        float wv = 0.0f;
        if constexpr (MODE == 1) wv = woutb[gn];
#pragma unroll
        for (int mi = 0; mi < 4; ++mi) {
            const int gmb = row0 + mi * 16;
#pragma unroll
            for (int rr = 0; rr < 4; ++rr) {
                const int gm = gmb + rr;
                const float a = acc[mi][ni][rr];
                if constexpr (MODE == 0) {
                    float v = gelu_exact(a + bv) + (float)Ab[(size_t)gm * ldaE + gn];
                    Cout[(size_t)gm * ldc + gn] = (__bf16)v;
                } else if constexpr (MODE == 1) {
                    float v = gelu_exact(a + bv) + (float)Ab[(size_t)gm * ldaE + gn];
                    rowdot[mi * 4 + rr] += v * wv;
                } else if constexpr (MODE == 2) {
                    const int p0row = ((gm >> 8) << 1) | (gm & 1);
                    const int p1row = gm & 255;
                    float v = a + bv + P0[(size_t)p0row * 2048 + gn]
                                     + P1[(size_t)p1row * 2048 + gn];
                    Cout[(size_t)gm * ldc + gnl] = (__bf16)gelu_exact(v);
                } else if constexpr (MODE == 3) {
                    float* Cfw = (DUAL && branch) ? Cf1 : Cf0;
                    Cfw[(size_t)gm * ldc + gn] = a;
                } else {
                    C0[(size_t)gm * ldc + gn] = (__bf16)a;
                }
            }
        }
    }

    if constexpr (MODE == 1) {
#pragma unroll
        for (int s = 1; s < 16; s <<= 1)
#pragma unroll
            for (int q = 0; q < 16; ++q) rowdot[q] += __shfl_xor(rowdot[q], s);
        if (lm == 0) {
            float* dotb = branch ? dot1 : dot0;
            float* dp = dotb + (size_t)(bn * 2 + wn) * 32768 + row0;
#pragma unroll
            for (int q = 0; q < 16; ++q)
                dp[(q >> 2) * 16 + (q & 3)] = rowdot[q];
        }
    }
}

// ---------------------------------------------------------------------------
// finalize: sum 16 (bn,wn)-partials per row; block = (b,j), reduce over i
// ---------------------------------------------------------------------------
__global__ __launch_bounds__(128)
void finalize(const float* __restrict__ dot_e, const float* __restrict__ dot_f,
              const float* __restrict__ eb, const float* __restrict__ fb,
              const float* __restrict__ vec, float* __restrict__ out) {
    const int bj = blockIdx.x;
    const int bb = bj >> 7, jj = bj & 127;
    const int i = threadIdx.x;
    const int m = (i * 128 + jj) * 2 + bb;
    float e = eb[0], f = fb[0];
#pragma unroll
    for (int s = 0; s < 16; ++s) {
        e += dot_e[(size_t)s * 32768 + m];
        f += dot_f[(size_t)s * 32768 + m];
    }
    f *= (1.0f / 60.0f);
    float fx = f * vec[(size_t)m * 3 + 0];
    float fy = f * vec[(size_t)m * 3 + 1];
    float fz = f * vec[(size_t)m * 3 + 2];
#pragma unroll
    for (int off = 32; off > 0; off >>= 1) {
        e  += __shfl_down(e, off);
        fx += __shfl_down(fx, off);
        fy += __shfl_down(fy, off);
        fz += __shfl_down(fz, off);
    }
    __shared__ float red[2][4];
    const int wv = i >> 6, lane = i & 63;
    if (lane == 0) { red[wv][0] = e; red[wv][1] = fx; red[wv][2] = fy; red[wv][3] = fz; }
    __syncthreads();
    if (i == 0) {
        atomicAdd(&out[bb], (red[0][0] + red[1][0]) * (1.0f / 3600.0f));
        float* fo = out + 2 + bj * 3;
        fo[0] = red[0][1] + red[1][1];
        fo[1] = red[0][2] + red[1][2];
        fo[2] = red[0][3] + red[1][3];
    }
}

// ---------------------------------------------------------------------------
extern "C" void kernel_launch(void* const* d_in, const int* in_sizes, int n_in,
                              void* d_out, int out_size, void* d_ws, size_t ws_size,
                              hipStream_t stream) {
    const float* x     = (const float*)d_in[0];
    const float* dist  = (const float*)d_in[1];
    const float* vec   = (const float*)d_in[2];
    const float* rbfW  = (const float*)d_in[4];
    const float* rbf_b = (const float*)d_in[5];
    const float* eWin  = (const float*)d_in[6];
    const float* ebin  = (const float*)d_in[7];
    const float* eWh   = (const float*)d_in[8];
    const float* ebh   = (const float*)d_in[9];
    const float* eWout = (const float*)d_in[10];
    const float* ebout = (const float*)d_in[11];
    const float* fWin  = (const float*)d_in[12];
    const float* fbin  = (const float*)d_in[13];
    const float* fWh   = (const float*)d_in[14];
    const float* fbh   = (const float*)d_in[15];
    const float* fWout = (const float*)d_in[16];
    const float* fbout = (const float*)d_in[17];
    float* out = (float*)d_out;

    // workspace carve (~225 MB, proven fits in rounds 2/4/5)
    char* p = (char*)d_ws;
    __bf16* WinTcat = (__bf16*)p;
    __bf16* eWinT = WinTcat;          p += (size_t)1024 * 1536 * 2;
    __bf16* fWinT = (__bf16*)p;       p += (size_t)1024 * 1536 * 2;
    __bf16* eWhT0 = (__bf16*)p;       p += (size_t)3 * 1024 * 1024 * 2;
    __bf16* fWhT0 = (__bf16*)p;       p += (size_t)3 * 1024 * 1024 * 2;
    __bf16* xb  = (__bf16*)p;         p += (size_t)256 * 512 * 2;
    __bf16* M1  = (__bf16*)p;         p += (size_t)128 * 512 * 2;
    __bf16* WgT = (__bf16*)p;         p += (size_t)2048 * 128 * 2;
    __bf16* G   = (__bf16*)p;         p += (size_t)32768 * 64 * 2;
    float* P0   = (float*)p;          p += (size_t)256 * 2048 * 4;
    float* P1   = (float*)p;          p += (size_t)256 * 2048 * 4;
    float* dot_e = (float*)p;         p += (size_t)16 * 32768 * 4;
    float* dot_f = (float*)p;         p += (size_t)16 * 32768 * 4;
    __bf16* he0  = (__bf16*)p;        p += (size_t)32768 * 1024 * 2;
    __bf16* hf0  = (__bf16*)p;        p += (size_t)32768 * 1024 * 2;
    __bf16* hAlt = (__bf16*)p;        p += (size_t)32768 * 1024 * 2;

    zero_out<<<dim3(4), dim3(256), 0, stream>>>(out, 770);

    // weight prep (merged via grid.z)
    transpose_multi<<<dim3(24, 16, 2), dim3(256), 0, stream>>>(
        eWin, fWin, eWinT, fWinT, 1536, 1024, 1);
    transpose_multi<<<dim3(16, 16, 6), dim3(256), 0, stream>>>(
        eWh, fWh, eWhT0, fWhT0, 1024, 1024, 3);
    f32_to_bf16<<<dim3(128), dim3(256), 0, stream>>>(x, xb, 131072);
    build_M1<<<dim3(128), dim3(256), 0, stream>>>(rbfW, rbf_b, M1);
    build_G<<<dim3(1024), dim3(256), 0, stream>>>(dist, G);

    const dim3 blk(256);
    // P0|P1 merged: x(256x512) @ Win[0:512) / [512:1024) -> f32 (256x2048)
    gemm_k<16, 16, 3, true><<<dim3(64), blk, 0, stream>>>(
        xb, xb, WinTcat, WinTcat + 512, 1024, 3072, 2048,
        nullptr, nullptr, nullptr, nullptr, P0, P1,
        nullptr, nullptr, nullptr, nullptr, nullptr, nullptr);
    // WgT(2048x128) = WinTcat[:,1024:1536] @ M1^T (bf16 raw)
    gemm_k<16, 1, 4, false><<<dim3(16), blk, 0, stream>>>(
        WinTcat + 1024, nullptr, M1, nullptr, 3072, 1024, 128,
        nullptr, nullptr, WgT, nullptr, nullptr, nullptr,
        nullptr, nullptr, nullptr, nullptr, nullptr, nullptr);
    // layer 0: he0|hf0 = gelu(G @ Wg + bias + P0[i,b] + P1[j,b])
    gemm_k<2, 16, 2, false><<<dim3(4096), blk, 0, stream>>>(
        G, nullptr, WgT, nullptr, 128, 256, 1024,
        ebin, fbin, he0, hf0, nullptr, nullptr, P0, P1,
        nullptr, nullptr, nullptr, nullptr);

    // hidden layers (branch-serial: hAlt shared; f starts after e's H2 frees it)
    gemm_k<32, 8, 0, false><<<dim3(2048), blk, 0, stream>>>(
        he0, nullptr, eWhT0, nullptr, 2048, 2048, 1024,
        ebh + 0, nullptr, hAlt, nullptr, nullptr, nullptr,
        nullptr, nullptr, nullptr, nullptr, nullptr, nullptr);
    gemm_k<32, 8, 0, false><<<dim3(2048), blk, 0, stream>>>(
        hAlt, nullptr, eWhT0 + (size_t)1048576, nullptr, 2048, 2048, 1024,
        ebh + 1024, nullptr, he0, nullptr, nullptr, nullptr,
        nullptr, nullptr, nullptr, nullptr, nullptr, nullptr);
    gemm_k<32, 8, 0, false><<<dim3(2048), blk, 0, stream>>>(
        hf0, nullptr, fWhT0, nullptr, 2048, 2048, 1024,
        fbh + 0, nullptr, hAlt, nullptr, nullptr, nullptr,
        nullptr, nullptr, nullptr, nullptr, nullptr, nullptr);
    gemm_k<32, 8, 0, false><<<dim3(2048), blk, 0, stream>>>(
        hAlt, nullptr, fWhT0 + (size_t)1048576, nullptr, 2048, 2048, 1024,
        fbh + 1024, nullptr, hf0, nullptr, nullptr, nullptr,
        nullptr, nullptr, nullptr, nullptr, nullptr, nullptr);
    // merged HEAD: layer-3 of both branches, dots only (no h3 materialized)
    gemm_k<32, 8, 1, true><<<dim3(4096), blk, 0, stream>>>(
        he0, hf0, eWhT0 + (size_t)2 * 1048576, fWhT0 + (size_t)2 * 1048576,
        2048, 2048, 1024, ebh + 2048, fbh + 2048,
        nullptr, nullptr, nullptr, nullptr, nullptr, nullptr,
        eWout, fWout, dot_e, dot_f);

    finalize<<<dim3(256), dim3(128), 0, stream>>>(dot_e, dot_f, ebout, fbout, vec, out);
}

// Round 7
// 1168.400 us; speedup vs baseline: 1.6024x; 1.0924x over previous
//
#include <hip/hip_runtime.h>
#include <stdint.h>

typedef __bf16 bf16x8 __attribute__((ext_vector_type(8)));
typedef __bf16 bf16x4 __attribute__((ext_vector_type(4)));
typedef float  f32x4  __attribute__((ext_vector_type(4)));
typedef unsigned int u32;

__device__ __forceinline__ void gl_lds16(const void* gptr, void* lptr) {
    __builtin_amdgcn_global_load_lds(
        (const __attribute__((address_space(1))) u32*)gptr,
        (__attribute__((address_space(3))) u32*)lptr,
        16, 0, 0);
}

__device__ __forceinline__ float gelu_exact(float x) {
    return 0.5f * x * (1.0f + erff(x * 0.70710678118654752f));
}

#define MEMFENCE __asm__ __volatile__("" ::: "memory")

__global__ void zero_out(float* __restrict__ o, int n) {
    int i = blockIdx.x * 256 + threadIdx.x;
    if (i < n) o[i] = 0.0f;
}

// ---------------------------------------------------------------------------
// fp32 [K][N] -> bf16 transposed [N][K]; z selects (branch,l) pair
// ---------------------------------------------------------------------------
__global__ __launch_bounds__(256)
void transpose_multi(const float* __restrict__ src0, const float* __restrict__ src1,
                     __bf16* __restrict__ dst0, __bf16* __restrict__ dst1,
                     int K, int Ncols, int perBranch) {
    const int z = blockIdx.z;
    const int branch = z / perBranch;
    const int l = z - branch * perBranch;
    const size_t elems = (size_t)K * Ncols;
    const float* src = (branch ? src1 : src0) + (size_t)l * elems;
    __bf16* dst = (branch ? dst1 : dst0) + (size_t)l * elems;

    __shared__ float tile[64][65];
    const int bk = blockIdx.x * 64;
    const int bn = blockIdx.y * 64;
    const int tid = threadIdx.x;
    const int tr = tid >> 4;
    const int tc = (tid & 15) * 4;
#pragma unroll
    for (int p = 0; p < 4; ++p) {
        const int r = tr + p * 16;
        float4 v = *(const float4*)&src[(size_t)(bk + r) * Ncols + bn + tc];
        tile[r][tc] = v.x; tile[r][tc + 1] = v.y;
        tile[r][tc + 2] = v.z; tile[r][tc + 3] = v.w;
    }
    __syncthreads();
#pragma unroll
    for (int p = 0; p < 4; ++p) {
        const int rn = tr + p * 16;
        bf16x4 o;
        o[0] = (__bf16)tile[tc + 0][rn];
        o[1] = (__bf16)tile[tc + 1][rn];
        o[2] = (__bf16)tile[tc + 2][rn];
        o[3] = (__bf16)tile[tc + 3][rn];
        *(bf16x4*)&dst[(size_t)(bn + rn) * K + bk + tc] = o;
    }
}

__global__ void f32_to_bf16(const float* __restrict__ s, __bf16* __restrict__ d, int n) {
    int idx = blockIdx.x * 256 + threadIdx.x;
    if (idx * 4 < n) {
        float4 v = *(const float4*)(s + idx * 4);
        bf16x4 o;
        o[0] = (__bf16)v.x; o[1] = (__bf16)v.y; o[2] = (__bf16)v.z; o[3] = (__bf16)v.w;
        *(bf16x4*)(d + idx * 4) = o;
    }
}

// M1 bf16 [128][512]: rows 0..49 = rbf_W, row 50 = rbf_b, rows 51..127 = 0
__global__ void build_M1(const float* __restrict__ rbfW, const float* __restrict__ rbf_b,
                         __bf16* __restrict__ M1) {
    int t = blockIdx.x * 256 + threadIdx.x;
    int r = t >> 8;
    int c = (t & 255) * 2;
    float v0 = 0.f, v1 = 0.f;
    if (r < 50)       { v0 = rbfW[r * 512 + c]; v1 = rbfW[r * 512 + c + 1]; }
    else if (r == 50) { v0 = rbf_b[c];          v1 = rbf_b[c + 1]; }
    M1[r * 512 + c] = (__bf16)v0;
    M1[r * 512 + c + 1] = (__bf16)v1;
}

// G bf16 [32768][64]: cols 0..49 = exp(coeff*(dist-k*sp)^2), col 50 = 1, rest 0
__global__ __launch_bounds__(256)
void build_G(const float* __restrict__ dist, __bf16* __restrict__ G) {
    const int t = threadIdx.x;
    const int row = blockIdx.x * 32 + (t >> 3);
    const int c0 = (t & 7) * 8;
    const float sp = 12.0f / 49.0f;
    const float coeff = -0.5f / (sp * sp);
    const float d = dist[row];
    bf16x8 v;
#pragma unroll
    for (int q = 0; q < 8; ++q) {
        const int k = c0 + q;
        float val;
        if (k < 50)       { float tt = d - (float)k * sp; val = __expf(coeff * tt * tt); }
        else if (k == 50) val = 1.0f;
        else              val = 0.0f;
        v[q] = (__bf16)val;
    }
    *(bf16x8*)(G + (size_t)row * 64 + c0) = v;
}

// ---------------------------------------------------------------------------
// 128x128-tile MFMA GEMM. 3-stage LDS pipeline, ONE barrier per K-step.
// MINW: min waves/EU for __launch_bounds__. MODE 1 (HEAD) needs ~172 VGPR ->
// MINW=2 (cap 256, no spill); MODE 0/2 fit under 168 -> MINW=3.
// DUAL: grid doubled, high half = f-branch (A1/B1/bias1/C1/...).
// MODE 0 HID : C = gelu(acc+bias)+A
// MODE 1 HEAD: rowdot(gelu(acc+bias)+A, wout) -> dot[(bn*2+wn)*32768+m]
// MODE 2 L0  : gelu(acc + bias + P0 + P1) -> he0/hf0 (side = bn>=8)
// MODE 3 RAWF32 : Cf = acc
// MODE 4 RAWBF16: C0 = (bf16)acc
// ---------------------------------------------------------------------------
template <int NK, int NBN, int MODE, bool DUAL, int MINW>
__global__ __launch_bounds__(256, MINW)
void gemm_k(const __bf16* __restrict__ A0, const __bf16* __restrict__ A1,
            const __bf16* __restrict__ B0, const __bf16* __restrict__ B1,
            int lda, int ldb, int ldc,
            const float* __restrict__ bias0, const float* __restrict__ bias1,
            __bf16* __restrict__ C0, __bf16* __restrict__ C1,
            float* __restrict__ Cf0, float* __restrict__ Cf1,
            const float* __restrict__ P0, const float* __restrict__ P1,
            const float* __restrict__ wout0, const float* __restrict__ wout1,
            float* __restrict__ dot0, float* __restrict__ dot1) {
    constexpr int NBS = (NBN == 16) ? 4 : (NBN == 8) ? 3 : 0;
    __shared__ __align__(16) __bf16 As[3][128 * 32];
    __shared__ __align__(16) __bf16 Bs[3][128 * 32];

    const int tid = threadIdx.x;
    int f2 = blockIdx.x;
    int branch = 0;
    if constexpr (DUAL) {
        const int half = gridDim.x >> 1;
        branch = (f2 >= half);
        if (branch) f2 -= half;
    }
    const int bn = f2 & (NBN - 1);
    const int bm = f2 >> NBS;
    const int w = tid >> 6;
    const int lane = tid & 63;

    const __bf16* Ab = (DUAL && branch) ? A1 : A0;
    const __bf16* Bb = (DUAL && branch) ? B1 : B0;

    const int r0 = tid >> 2;
    const int s0 = tid & 3;
    const char* gA0 = (const char*)Ab + (size_t)(bm * 128 + r0) * lda + s0 * 16;
    const char* gA1 = gA0 + (size_t)64 * lda;
    const char* gB0 = (const char*)Bb + (size_t)(bn * 128 + r0) * ldb + s0 * 16;
    const char* gB1 = gB0 + (size_t)64 * ldb;

    char* lA0 = (char*)&As[0][0] + w * 1024;
    char* lA1 = (char*)&As[1][0] + w * 1024;
    char* lA2 = (char*)&As[2][0] + w * 1024;
    char* lB0 = (char*)&Bs[0][0] + w * 1024;
    char* lB1 = (char*)&Bs[1][0] + w * 1024;
    char* lB2 = (char*)&Bs[2][0] + w * 1024;

    const int wm = (w >> 1) & 1;
    const int wn = w & 1;
    const int lm = lane & 15;
    const int ko = (lane >> 4) << 3;
    const int fo = (wm * 64 + lm) * 32 + ko;
    const int go = (wn * 64 + lm) * 32 + ko;
    const __bf16* pA0 = &As[0][0] + fo;
    const __bf16* pA1 = &As[1][0] + fo;
    const __bf16* pA2 = &As[2][0] + fo;
    const __bf16* pB0 = &Bs[0][0] + go;
    const __bf16* pB1 = &Bs[1][0] + go;
    const __bf16* pB2 = &Bs[2][0] + go;

    f32x4 acc[4][4];
    const f32x4 zero = {0.0f, 0.0f, 0.0f, 0.0f};
#pragma unroll
    for (int i = 0; i < 4; ++i)
#pragma unroll
        for (int j = 0; j < 4; ++j) acc[i][j] = zero;

    auto stage = [&](int buf) {   // buf literal at every call site
        char* la = (buf == 0) ? lA0 : (buf == 1) ? lA1 : lA2;
        char* lb = (buf == 0) ? lB0 : (buf == 1) ? lB1 : lB2;
        gl_lds16(gA0, la); gl_lds16(gA1, la + 4096);
        gl_lds16(gB0, lb); gl_lds16(gB1, lb + 4096);
        gA0 += 64; gA1 += 64; gB0 += 64; gB1 += 64;
    };
    auto compute = [&](int buf) {
        const __bf16* pa = (buf == 0) ? pA0 : (buf == 1) ? pA1 : pA2;
        const __bf16* pb = (buf == 0) ? pB0 : (buf == 1) ? pB1 : pB2;
        bf16x8 af[4], bfg[4];
#pragma unroll
        for (int i = 0; i < 4; ++i) {
            af[i]  = *(const bf16x8*)(pa + i * 512);
            bfg[i] = *(const bf16x8*)(pb + i * 512);
        }
#pragma unroll
        for (int mi = 0; mi < 4; ++mi)
#pragma unroll
            for (int ni = 0; ni < 4; ++ni)
                acc[mi][ni] = __builtin_amdgcn_mfma_f32_16x16x32_bf16(
                    af[mi], bfg[ni], acc[mi][ni], 0, 0, 0);
    };
    auto iterstep = [&](int cbuf, int sbuf) {
        MEMFENCE;
        __builtin_amdgcn_s_waitcnt(0xF74);   // vmcnt(4): cbuf's 4 loads landed
        __builtin_amdgcn_s_barrier();
        MEMFENCE;
        compute(cbuf);
        MEMFENCE;
        stage(sbuf);                         // overwrites buffer computed last
        MEMFENCE;                            // iter -- barrier above separates
    };

    stage(0);
    stage(1);
    constexpr int NIT = NK - 2;
    constexpr int NG = NIT / 3;
    constexpr int NR = NIT % 3;
    for (int g = 0; g < NG; ++g) {           // runtime loop, constant indices
        iterstep(0, 2);
        iterstep(1, 0);
        iterstep(2, 1);
    }
    if constexpr (NR >= 1) iterstep(0, 2);
    if constexpr (NR >= 2) iterstep(1, 0);
    // tails (no more stages)
    MEMFENCE;
    __builtin_amdgcn_s_waitcnt(0xF74);       // vmcnt(4)
    __builtin_amdgcn_s_barrier();
    MEMFENCE;
    compute((NK - 2) % 3);
    MEMFENCE;
    __builtin_amdgcn_s_waitcnt(0xF70);       // vmcnt(0)
    __builtin_amdgcn_s_barrier();
    MEMFENCE;
    compute((NK - 1) % 3);

    // epilogue: C/D layout col = lane&15, row = (lane>>4)*4 + reg
    const int col0 = bn * 128 + wn * 64 + lm;
    const int row0 = bm * 128 + wm * 64 + ((lane >> 4) << 2);
    const int ldaE = lda >> 1;

    float rowdot[16];
    if constexpr (MODE == 1) {
#pragma unroll
        for (int q = 0; q < 16; ++q) rowdot[q] = 0.0f;
    }

    const bool side = (MODE == 2) && (bn >= 8);
    const float* bp = (MODE == 2) ? (side ? bias1 : bias0)
                                  : ((DUAL && branch) ? bias1 : bias0);
    __bf16* Cout = (MODE == 2) ? (side ? C1 : C0)
                               : ((DUAL && branch) ? C1 : C0);
    const float* woutb = (MODE == 1) ? ((DUAL && branch) ? wout1 : wout0) : nullptr;

#pragma unroll
    for (int ni = 0; ni < 4; ++ni) {
        const int gn = col0 + ni * 16;
        const int gnl = (MODE == 2) ? (gn & 1023) : gn;
        float bv = 0.0f;
        if constexpr (MODE <= 2) bv = bp[gnl];
        float wv = 0.0f;
        if constexpr (MODE == 1) wv = woutb[gn];
#pragma unroll
        for (int mi = 0; mi < 4; ++mi) {
            const int gmb = row0 + mi * 16;
#pragma unroll
            for (int rr = 0; rr < 4; ++rr) {
                const int gm = gmb + rr;
                const float a = acc[mi][ni][rr];
                if constexpr (MODE == 0) {
                    float v = gelu_exact(a + bv) + (float)Ab[(size_t)gm * ldaE + gn];
                    Cout[(size_t)gm * ldc + gn] = (__bf16)v;
                } else if constexpr (MODE == 1) {
                    float v = gelu_exact(a + bv) + (float)Ab[(size_t)gm * ldaE + gn];
                    rowdot[mi * 4 + rr] += v * wv;
                } else if constexpr (MODE == 2) {
                    const int p0row = ((gm >> 8) << 1) | (gm & 1);
                    const int p1row = gm & 255;
                    float v = a + bv + P0[(size_t)p0row * 2048 + gn]
                                     + P1[(size_t)p1row * 2048 + gn];
                    Cout[(size_t)gm * ldc + gnl] = (__bf16)gelu_exact(v);
                } else if constexpr (MODE == 3) {
                    float* Cfw = (DUAL && branch) ? Cf1 : Cf0;
                    Cfw[(size_t)gm * ldc + gn] = a;
                } else {
                    C0[(size_t)gm * ldc + gn] = (__bf16)a;
                }
            }
        }
    }

    if constexpr (MODE == 1) {
#pragma unroll
        for (int s = 1; s < 16; s <<= 1)
#pragma unroll
            for (int q = 0; q < 16; ++q) rowdot[q] += __shfl_xor(rowdot[q], s);
        if (lm == 0) {
            float* dotb = (DUAL && branch) ? dot1 : dot0;
            float* dp = dotb + (size_t)(bn * 2 + wn) * 32768 + row0;
#pragma unroll
            for (int q = 0; q < 16; ++q)
                dp[(q >> 2) * 16 + (q & 3)] = rowdot[q];
        }
    }
}

// ---------------------------------------------------------------------------
// finalize: sum 16 (bn,wn)-partials per row; block = (b,j), reduce over i
// ---------------------------------------------------------------------------
__global__ __launch_bounds__(128)
void finalize(const float* __restrict__ dot_e, const float* __restrict__ dot_f,
              const float* __restrict__ eb, const float* __restrict__ fb,
              const float* __restrict__ vec, float* __restrict__ out) {
    const int bj = blockIdx.x;
    const int bb = bj >> 7, jj = bj & 127;
    const int i = threadIdx.x;
    const int m = (i * 128 + jj) * 2 + bb;
    float e = eb[0], f = fb[0];
#pragma unroll
    for (int s = 0; s < 16; ++s) {
        e += dot_e[(size_t)s * 32768 + m];
        f += dot_f[(size_t)s * 32768 + m];
    }
    f *= (1.0f / 60.0f);
    float fx = f * vec[(size_t)m * 3 + 0];
    float fy = f * vec[(size_t)m * 3 + 1];
    float fz = f * vec[(size_t)m * 3 + 2];
#pragma unroll
    for (int off = 32; off > 0; off >>= 1) {
        e  += __shfl_down(e, off);
        fx += __shfl_down(fx, off);
        fy += __shfl_down(fy, off);
        fz += __shfl_down(fz, off);
    }
    __shared__ float red[2][4];
    const int wv = i >> 6, lane = i & 63;
    if (lane == 0) { red[wv][0] = e; red[wv][1] = fx; red[wv][2] = fy; red[wv][3] = fz; }
    __syncthreads();
    if (i == 0) {
        atomicAdd(&out[bb], (red[0][0] + red[1][0]) * (1.0f / 3600.0f));
        float* fo = out + 2 + bj * 3;
        fo[0] = red[0][1] + red[1][1];
        fo[1] = red[0][2] + red[1][2];
        fo[2] = red[0][3] + red[1][3];
    }
}

// ---------------------------------------------------------------------------
extern "C" void kernel_launch(void* const* d_in, const int* in_sizes, int n_in,
                              void* d_out, int out_size, void* d_ws, size_t ws_size,
                              hipStream_t stream) {
    const float* x     = (const float*)d_in[0];
    const float* dist  = (const float*)d_in[1];
    const float* vec   = (const float*)d_in[2];
    const float* rbfW  = (const float*)d_in[4];
    const float* rbf_b = (const float*)d_in[5];
    const float* eWin  = (const float*)d_in[6];
    const float* ebin  = (const float*)d_in[7];
    const float* eWh   = (const float*)d_in[8];
    const float* ebh   = (const float*)d_in[9];
    const float* eWout = (const float*)d_in[10];
    const float* ebout = (const float*)d_in[11];
    const float* fWin  = (const float*)d_in[12];
    const float* fbin  = (const float*)d_in[13];
    const float* fWh   = (const float*)d_in[14];
    const float* fbh   = (const float*)d_in[15];
    const float* fWout = (const float*)d_in[16];
    const float* fbout = (const float*)d_in[17];
    float* out = (float*)d_out;

    // workspace carve (3-slab base ~234 MB, proven fits; 4th slab conditional)
    char* p = (char*)d_ws;
    __bf16* WinTcat = (__bf16*)p;
    __bf16* eWinT = WinTcat;          p += (size_t)1024 * 1536 * 2;
    __bf16* fWinT = (__bf16*)p;       p += (size_t)1024 * 1536 * 2;
    __bf16* eWhT0 = (__bf16*)p;       p += (size_t)3 * 1024 * 1024 * 2;
    __bf16* fWhT0 = (__bf16*)p;       p += (size_t)3 * 1024 * 1024 * 2;
    __bf16* xb  = (__bf16*)p;         p += (size_t)256 * 512 * 2;
    __bf16* M1  = (__bf16*)p;         p += (size_t)128 * 512 * 2;
    __bf16* WgT = (__bf16*)p;         p += (size_t)2048 * 128 * 2;
    __bf16* G   = (__bf16*)p;         p += (size_t)32768 * 64 * 2;
    float* P0   = (float*)p;          p += (size_t)256 * 2048 * 4;
    float* P1   = (float*)p;          p += (size_t)256 * 2048 * 4;
    float* dot_e = (float*)p;         p += (size_t)16 * 32768 * 4;
    float* dot_f = (float*)p;         p += (size_t)16 * 32768 * 4;
    const size_t SLAB = (size_t)32768 * 1024 * 2;   // 64 MB
    __bf16* he0 = (__bf16*)p;         p += SLAB;
    __bf16* hf0 = (__bf16*)p;         p += SLAB;
    __bf16* hAe = (__bf16*)p;         p += SLAB;    // serial: shared hAlt
    __bf16* hAf = hAe;
    const bool dualHidden = ((size_t)(p - (char*)d_ws) + SLAB) <= ws_size;
    if (dualHidden) hAf = (__bf16*)p;               // 4th slab fits

    zero_out<<<dim3(4), dim3(256), 0, stream>>>(out, 770);

    // weight prep (merged via grid.z)
    transpose_multi<<<dim3(24, 16, 2), dim3(256), 0, stream>>>(
        eWin, fWin, eWinT, fWinT, 1536, 1024, 1);
    transpose_multi<<<dim3(16, 16, 6), dim3(256), 0, stream>>>(
        eWh, fWh, eWhT0, fWhT0, 1024, 1024, 3);
    f32_to_bf16<<<dim3(128), dim3(256), 0, stream>>>(x, xb, 131072);
    build_M1<<<dim3(128), dim3(256), 0, stream>>>(rbfW, rbf_b, M1);
    build_G<<<dim3(1024), dim3(256), 0, stream>>>(dist, G);

    const dim3 blk(256);
    // P0|P1 merged: x(256x512) @ Win[0:512) / [512:1024) -> f32 (256x2048)
    gemm_k<16, 16, 3, true, 3><<<dim3(64), blk, 0, stream>>>(
        xb, xb, WinTcat, WinTcat + 512, 1024, 3072, 2048,
        nullptr, nullptr, nullptr, nullptr, P0, P1,
        nullptr, nullptr, nullptr, nullptr, nullptr, nullptr);
    // WgT(2048x128) = WinTcat[:,1024:1536] @ M1^T (bf16 raw)
    gemm_k<16, 1, 4, false, 3><<<dim3(16), blk, 0, stream>>>(
        WinTcat + 1024, nullptr, M1, nullptr, 3072, 1024, 128,
        nullptr, nullptr, WgT, nullptr, nullptr, nullptr,
        nullptr, nullptr, nullptr, nullptr, nullptr, nullptr);
    // layer 0: he0|hf0 = gelu(G @ Wg + bias + P0[i,b] + P1[j,b])
    gemm_k<2, 16, 2, false, 3><<<dim3(4096), blk, 0, stream>>>(
        G, nullptr, WgT, nullptr, 128, 256, 1024,
        ebin, fbin, he0, hf0, nullptr, nullptr, P0, P1,
        nullptr, nullptr, nullptr, nullptr);

    if (dualHidden) {
        // both branches per dispatch (4 slabs)
        gemm_k<32, 8, 0, true, 3><<<dim3(4096), blk, 0, stream>>>(
            he0, hf0, eWhT0, fWhT0, 2048, 2048, 1024,
            ebh + 0, fbh + 0, hAe, hAf, nullptr, nullptr,
            nullptr, nullptr, nullptr, nullptr, nullptr, nullptr);
        gemm_k<32, 8, 0, true, 3><<<dim3(4096), blk, 0, stream>>>(
            hAe, hAf, eWhT0 + (size_t)1048576, fWhT0 + (size_t)1048576,
            2048, 2048, 1024, ebh + 1024, fbh + 1024, he0, hf0,
            nullptr, nullptr, nullptr, nullptr, nullptr, nullptr, nullptr, nullptr);
    } else {
        // branch-serial fallback (3 slabs, hAe==hAf)
        gemm_k<32, 8, 0, false, 3><<<dim3(2048), blk, 0, stream>>>(
            he0, nullptr, eWhT0, nullptr, 2048, 2048, 1024,
            ebh + 0, nullptr, hAe, nullptr, nullptr, nullptr,
            nullptr, nullptr, nullptr, nullptr, nullptr, nullptr);
        gemm_k<32, 8, 0, false, 3><<<dim3(2048), blk, 0, stream>>>(
            hAe, nullptr, eWhT0 + (size_t)1048576, nullptr, 2048, 2048, 1024,
            ebh + 1024, nullptr, he0, nullptr, nullptr, nullptr,
            nullptr, nullptr, nullptr, nullptr, nullptr, nullptr);
        gemm_k<32, 8, 0, false, 3><<<dim3(2048), blk, 0, stream>>>(
            hf0, nullptr, fWhT0, nullptr, 2048, 2048, 1024,
            fbh + 0, nullptr, hAf, nullptr, nullptr, nullptr,
            nullptr, nullptr, nullptr, nullptr, nullptr, nullptr);
        gemm_k<32, 8, 0, false, 3><<<dim3(2048), blk, 0, stream>>>(
            hAf, nullptr, fWhT0 + (size_t)1048576, nullptr, 2048, 2048, 1024,
            fbh + 1024, nullptr, hf0, nullptr, nullptr, nullptr,
            nullptr, nullptr, nullptr, nullptr, nullptr, nullptr);
    }
    // merged HEAD (MINW=2: needs ~172 VGPR; cap 256 avoids round-6 spill)
    gemm_k<32, 8, 1, true, 2><<<dim3(4096), blk, 0, stream>>>(
        he0, hf0, eWhT0 + (size_t)2 * 1048576, fWhT0 + (size_t)2 * 1048576,
        2048, 2048, 1024, ebh + 2048, fbh + 2048,
        nullptr, nullptr, nullptr, nullptr, nullptr, nullptr,
        eWout, fWout, dot_e, dot_f);

    finalize<<<dim3(256), dim3(128), 0, stream>>>(dot_e, dot_f, ebout, fbout, vec, out);
}

// Round 8
// 1131.930 us; speedup vs baseline: 1.6540x; 1.0322x over previous
//
#include <hip/hip_runtime.h>
#include <stdint.h>

typedef __bf16 bf16x8 __attribute__((ext_vector_type(8)));
typedef __bf16 bf16x4 __attribute__((ext_vector_type(4)));
typedef float  f32x4  __attribute__((ext_vector_type(4)));
typedef unsigned int u32;

__device__ __forceinline__ void gl_lds16(const void* gptr, void* lptr) {
    __builtin_amdgcn_global_load_lds(
        (const __attribute__((address_space(1))) u32*)gptr,
        (__attribute__((address_space(3))) u32*)lptr,
        16, 0, 0);
}

__device__ __forceinline__ float gelu_exact(float x) {
    return 0.5f * x * (1.0f + erff(x * 0.70710678118654752f));
}

#define MEMFENCE __asm__ __volatile__("" ::: "memory")

__global__ void zero_out(float* __restrict__ o, int n) {
    int i = blockIdx.x * 256 + threadIdx.x;
    if (i < n) o[i] = 0.0f;
}

// ---------------------------------------------------------------------------
// fp32 [K][N] -> bf16 transposed [N][K]; z selects (branch,l) pair
// ---------------------------------------------------------------------------
__global__ __launch_bounds__(256)
void transpose_multi(const float* __restrict__ src0, const float* __restrict__ src1,
                     __bf16* __restrict__ dst0, __bf16* __restrict__ dst1,
                     int K, int Ncols, int perBranch) {
    const int z = blockIdx.z;
    const int branch = z / perBranch;
    const int l = z - branch * perBranch;
    const size_t elems = (size_t)K * Ncols;
    const float* src = (branch ? src1 : src0) + (size_t)l * elems;
    __bf16* dst = (branch ? dst1 : dst0) + (size_t)l * elems;

    __shared__ float tile[64][65];
    const int bk = blockIdx.x * 64;
    const int bn = blockIdx.y * 64;
    const int tid = threadIdx.x;
    const int tr = tid >> 4;
    const int tc = (tid & 15) * 4;
#pragma unroll
    for (int p = 0; p < 4; ++p) {
        const int r = tr + p * 16;
        float4 v = *(const float4*)&src[(size_t)(bk + r) * Ncols + bn + tc];
        tile[r][tc] = v.x; tile[r][tc + 1] = v.y;
        tile[r][tc + 2] = v.z; tile[r][tc + 3] = v.w;
    }
    __syncthreads();
#pragma unroll
    for (int p = 0; p < 4; ++p) {
        const int rn = tr + p * 16;
        bf16x4 o;
        o[0] = (__bf16)tile[tc + 0][rn];
        o[1] = (__bf16)tile[tc + 1][rn];
        o[2] = (__bf16)tile[tc + 2][rn];
        o[3] = (__bf16)tile[tc + 3][rn];
        *(bf16x4*)&dst[(size_t)(bn + rn) * K + bk + tc] = o;
    }
}

__global__ void f32_to_bf16(const float* __restrict__ s, __bf16* __restrict__ d, int n) {
    int idx = blockIdx.x * 256 + threadIdx.x;
    if (idx * 4 < n) {
        float4 v = *(const float4*)(s + idx * 4);
        bf16x4 o;
        o[0] = (__bf16)v.x; o[1] = (__bf16)v.y; o[2] = (__bf16)v.z; o[3] = (__bf16)v.w;
        *(bf16x4*)(d + idx * 4) = o;
    }
}

// M1 bf16 [128][512]: rows 0..49 = rbf_W, row 50 = rbf_b, rows 51..127 = 0
__global__ void build_M1(const float* __restrict__ rbfW, const float* __restrict__ rbf_b,
                         __bf16* __restrict__ M1) {
    int t = blockIdx.x * 256 + threadIdx.x;
    int r = t >> 8;
    int c = (t & 255) * 2;
    float v0 = 0.f, v1 = 0.f;
    if (r < 50)       { v0 = rbfW[r * 512 + c]; v1 = rbfW[r * 512 + c + 1]; }
    else if (r == 50) { v0 = rbf_b[c];          v1 = rbf_b[c + 1]; }
    M1[r * 512 + c] = (__bf16)v0;
    M1[r * 512 + c + 1] = (__bf16)v1;
}

// G bf16 [32768][64]: cols 0..49 = exp(coeff*(dist-k*sp)^2), col 50 = 1, rest 0
__global__ __launch_bounds__(256)
void build_G(const float* __restrict__ dist, __bf16* __restrict__ G) {
    const int t = threadIdx.x;
    const int row = blockIdx.x * 32 + (t >> 3);
    const int c0 = (t & 7) * 8;
    const float sp = 12.0f / 49.0f;
    const float coeff = -0.5f / (sp * sp);
    const float d = dist[row];
    bf16x8 v;
#pragma unroll
    for (int q = 0; q < 8; ++q) {
        const int k = c0 + q;
        float val;
        if (k < 50)       { float tt = d - (float)k * sp; val = __expf(coeff * tt * tt); }
        else if (k == 50) val = 1.0f;
        else              val = 0.0f;
        v[q] = (__bf16)val;
    }
    *(bf16x8*)(G + (size_t)row * 64 + c0) = v;
}

// ---------------------------------------------------------------------------
// 128x128-tile MFMA GEMM. 3-stage LDS pipeline, ONE barrier per K-step.
// SWZ (requires gridDim.x % (8*NBN) == 0): XCD-aware decode — blk%8 = XCD
// (HW round-robin), so put all NBN bn-siblings of one A-panel on ONE XCD as
// consecutive blocks: x=blk&7, slot=blk>>3, bn=slot&(NBN-1),
// grp=x+8*(slot>>NBS). Panel fetched once from HBM, N-1 L2 hits.
// MODE 0 HID : C = gelu(acc+bias)+A
// MODE 1 HEAD: rowdot(gelu(acc+bias)+A, wout) -> dot[(bn*2+wn)*32768+m]
// MODE 2 L0  : gelu(acc + bias + P0 + P1) -> he0/hf0 (side = bn>=8)
// MODE 3 RAWF32 : Cf = acc
// MODE 4 RAWBF16: C0 = (bf16)acc
// ---------------------------------------------------------------------------
template <int NK, int NBN, int MODE, bool DUAL, int MINW, bool SWZ>
__global__ __launch_bounds__(256, MINW)
void gemm_k(const __bf16* __restrict__ A0, const __bf16* __restrict__ A1,
            const __bf16* __restrict__ B0, const __bf16* __restrict__ B1,
            int lda, int ldb, int ldc,
            const float* __restrict__ bias0, const float* __restrict__ bias1,
            __bf16* __restrict__ C0, __bf16* __restrict__ C1,
            float* __restrict__ Cf0, float* __restrict__ Cf1,
            const float* __restrict__ P0, const float* __restrict__ P1,
            const float* __restrict__ wout0, const float* __restrict__ wout1,
            float* __restrict__ dot0, float* __restrict__ dot1) {
    constexpr int NBS = (NBN == 16) ? 4 : (NBN == 8) ? 3 : 0;
    __shared__ __align__(16) __bf16 As[3][128 * 32];
    __shared__ __align__(16) __bf16 Bs[3][128 * 32];

    const int tid = threadIdx.x;
    int bn, bm, branch = 0;
    if constexpr (SWZ) {
        const int x = blockIdx.x & 7;
        const int slot = blockIdx.x >> 3;
        bn = slot & (NBN - 1);
        int grp = x + ((slot >> NBS) << 3);
        if constexpr (DUAL) {
            const int half = (gridDim.x >> NBS) >> 1;   // total groups / 2
            branch = (grp >= half);
            if (branch) grp -= half;
        }
        bm = grp;
    } else {
        int f2 = blockIdx.x;
        if constexpr (DUAL) {
            const int half = gridDim.x >> 1;
            branch = (f2 >= half);
            if (branch) f2 -= half;
        }
        bn = f2 & (NBN - 1);
        bm = f2 >> NBS;
    }
    const int w = tid >> 6;
    const int lane = tid & 63;

    const __bf16* Ab = (DUAL && branch) ? A1 : A0;
    const __bf16* Bb = (DUAL && branch) ? B1 : B0;

    const int r0 = tid >> 2;
    const int s0 = tid & 3;
    const char* gA0 = (const char*)Ab + (size_t)(bm * 128 + r0) * lda + s0 * 16;
    const char* gA1 = gA0 + (size_t)64 * lda;
    const char* gB0 = (const char*)Bb + (size_t)(bn * 128 + r0) * ldb + s0 * 16;
    const char* gB1 = gB0 + (size_t)64 * ldb;

    char* lA0 = (char*)&As[0][0] + w * 1024;
    char* lA1 = (char*)&As[1][0] + w * 1024;
    char* lA2 = (char*)&As[2][0] + w * 1024;
    char* lB0 = (char*)&Bs[0][0] + w * 1024;
    char* lB1 = (char*)&Bs[1][0] + w * 1024;
    char* lB2 = (char*)&Bs[2][0] + w * 1024;

    const int wm = (w >> 1) & 1;
    const int wn = w & 1;
    const int lm = lane & 15;
    const int ko = (lane >> 4) << 3;
    const int fo = (wm * 64 + lm) * 32 + ko;
    const int go = (wn * 64 + lm) * 32 + ko;
    const __bf16* pA0 = &As[0][0] + fo;
    const __bf16* pA1 = &As[1][0] + fo;
    const __bf16* pA2 = &As[2][0] + fo;
    const __bf16* pB0 = &Bs[0][0] + go;
    const __bf16* pB1 = &Bs[1][0] + go;
    const __bf16* pB2 = &Bs[2][0] + go;

    f32x4 acc[4][4];
    const f32x4 zero = {0.0f, 0.0f, 0.0f, 0.0f};
#pragma unroll
    for (int i = 0; i < 4; ++i)
#pragma unroll
        for (int j = 0; j < 4; ++j) acc[i][j] = zero;

    auto stage = [&](int buf) {   // buf literal at every call site
        char* la = (buf == 0) ? lA0 : (buf == 1) ? lA1 : lA2;
        char* lb = (buf == 0) ? lB0 : (buf == 1) ? lB1 : lB2;
        gl_lds16(gA0, la); gl_lds16(gA1, la + 4096);
        gl_lds16(gB0, lb); gl_lds16(gB1, lb + 4096);
        gA0 += 64; gA1 += 64; gB0 += 64; gB1 += 64;
    };
    auto compute = [&](int buf) {
        const __bf16* pa = (buf == 0) ? pA0 : (buf == 1) ? pA1 : pA2;
        const __bf16* pb = (buf == 0) ? pB0 : (buf == 1) ? pB1 : pB2;
        bf16x8 af[4], bfg[4];
#pragma unroll
        for (int i = 0; i < 4; ++i) {
            af[i]  = *(const bf16x8*)(pa + i * 512);
            bfg[i] = *(const bf16x8*)(pb + i * 512);
        }
#pragma unroll
        for (int mi = 0; mi < 4; ++mi)
#pragma unroll
            for (int ni = 0; ni < 4; ++ni)
                acc[mi][ni] = __builtin_amdgcn_mfma_f32_16x16x32_bf16(
                    af[mi], bfg[ni], acc[mi][ni], 0, 0, 0);
    };
    auto iterstep = [&](int cbuf, int sbuf) {
        MEMFENCE;
        __builtin_amdgcn_s_waitcnt(0xF74);   // vmcnt(4): cbuf's 4 loads landed
        __builtin_amdgcn_s_barrier();
        MEMFENCE;
        compute(cbuf);
        MEMFENCE;
        stage(sbuf);                         // overwrites buffer computed last
        MEMFENCE;                            // iter -- barrier above separates
    };

    stage(0);
    stage(1);
    constexpr int NIT = NK - 2;
    constexpr int NG = NIT / 3;
    constexpr int NR = NIT % 3;
    for (int g = 0; g < NG; ++g) {           // runtime loop, constant indices
        iterstep(0, 2);
        iterstep(1, 0);
        iterstep(2, 1);
    }
    if constexpr (NR >= 1) iterstep(0, 2);
    if constexpr (NR >= 2) iterstep(1, 0);
    // tails (no more stages)
    MEMFENCE;
    __builtin_amdgcn_s_waitcnt(0xF74);       // vmcnt(4)
    __builtin_amdgcn_s_barrier();
    MEMFENCE;
    compute((NK - 2) % 3);
    MEMFENCE;
    __builtin_amdgcn_s_waitcnt(0xF70);       // vmcnt(0)
    __builtin_amdgcn_s_barrier();
    MEMFENCE;
    compute((NK - 1) % 3);

    // epilogue: C/D layout col = lane&15, row = (lane>>4)*4 + reg
    const int col0 = bn * 128 + wn * 64 + lm;
    const int row0 = bm * 128 + wm * 64 + ((lane >> 4) << 2);
    const int ldaE = lda >> 1;

    float rowdot[16];
    if constexpr (MODE == 1) {
#pragma unroll
        for (int q = 0; q < 16; ++q) rowdot[q] = 0.0f;
    }

    const bool side = (MODE == 2) && (bn >= 8);
    const float* bp = (MODE == 2) ? (side ? bias1 : bias0)
                                  : ((DUAL && branch) ? bias1 : bias0);
    __bf16* Cout = (MODE == 2) ? (side ? C1 : C0)
                               : ((DUAL && branch) ? C1 : C0);
    const float* woutb = (MODE == 1) ? ((DUAL && branch) ? wout1 : wout0) : nullptr;

#pragma unroll
    for (int ni = 0; ni < 4; ++ni) {
        const int gn = col0 + ni * 16;
        const int gnl = (MODE == 2) ? (gn & 1023) : gn;
        float bv = 0.0f;
        if constexpr (MODE <= 2) bv = bp[gnl];
        float wv = 0.0f;
        if constexpr (MODE == 1) wv = woutb[gn];
#pragma unroll
        for (int mi = 0; mi < 4; ++mi) {
            const int gmb = row0 + mi * 16;
#pragma unroll
            for (int rr = 0; rr < 4; ++rr) {
                const int gm = gmb + rr;
                const float a = acc[mi][ni][rr];
                if constexpr (MODE == 0) {
                    float v = gelu_exact(a + bv) + (float)Ab[(size_t)gm * ldaE + gn];
                    Cout[(size_t)gm * ldc + gn] = (__bf16)v;
                } else if constexpr (MODE == 1) {
                    float v = gelu_exact(a + bv) + (float)Ab[(size_t)gm * ldaE + gn];
                    rowdot[mi * 4 + rr] += v * wv;
                } else if constexpr (MODE == 2) {
                    const int p0row = ((gm >> 8) << 1) | (gm & 1);
                    const int p1row = gm & 255;
                    float v = a + bv + P0[(size_t)p0row * 2048 + gn]
                                     + P1[(size_t)p1row * 2048 + gn];
                    Cout[(size_t)gm * ldc + gnl] = (__bf16)gelu_exact(v);
                } else if constexpr (MODE == 3) {
                    float* Cfw = (DUAL && branch) ? Cf1 : Cf0;
                    Cfw[(size_t)gm * ldc + gn] = a;
                } else {
                    C0[(size_t)gm * ldc + gn] = (__bf16)a;
                }
            }
        }
    }

    if constexpr (MODE == 1) {
#pragma unroll
        for (int s = 1; s < 16; s <<= 1)
#pragma unroll
            for (int q = 0; q < 16; ++q) rowdot[q] += __shfl_xor(rowdot[q], s);
        if (lm == 0) {
            float* dotb = (DUAL && branch) ? dot1 : dot0;
            float* dp = dotb + (size_t)(bn * 2 + wn) * 32768 + row0;
#pragma unroll
            for (int q = 0; q < 16; ++q)
                dp[(q >> 2) * 16 + (q & 3)] = rowdot[q];
        }
    }
}

// ---------------------------------------------------------------------------
// finalize: sum 16 (bn,wn)-partials per row; block = (b,j), reduce over i
// ---------------------------------------------------------------------------
__global__ __launch_bounds__(128)
void finalize(const float* __restrict__ dot_e, const float* __restrict__ dot_f,
              const float* __restrict__ eb, const float* __restrict__ fb,
              const float* __restrict__ vec, float* __restrict__ out) {
    const int bj = blockIdx.x;
    const int bb = bj >> 7, jj = bj & 127;
    const int i = threadIdx.x;
    const int m = (i * 128 + jj) * 2 + bb;
    float e = eb[0], f = fb[0];
#pragma unroll
    for (int s = 0; s < 16; ++s) {
        e += dot_e[(size_t)s * 32768 + m];
        f += dot_f[(size_t)s * 32768 + m];
    }
    f *= (1.0f / 60.0f);
    float fx = f * vec[(size_t)m * 3 + 0];
    float fy = f * vec[(size_t)m * 3 + 1];
    float fz = f * vec[(size_t)m * 3 + 2];
#pragma unroll
    for (int off = 32; off > 0; off >>= 1) {
        e  += __shfl_down(e, off);
        fx += __shfl_down(fx, off);
        fy += __shfl_down(fy, off);
        fz += __shfl_down(fz, off);
    }
    __shared__ float red[2][4];
    const int wv = i >> 6, lane = i & 63;
    if (lane == 0) { red[wv][0] = e; red[wv][1] = fx; red[wv][2] = fy; red[wv][3] = fz; }
    __syncthreads();
    if (i == 0) {
        atomicAdd(&out[bb], (red[0][0] + red[1][0]) * (1.0f / 3600.0f));
        float* fo = out + 2 + bj * 3;
        fo[0] = red[0][1] + red[1][1];
        fo[1] = red[0][2] + red[1][2];
        fo[2] = red[0][3] + red[1][3];
    }
}

// ---------------------------------------------------------------------------
extern "C" void kernel_launch(void* const* d_in, const int* in_sizes, int n_in,
                              void* d_out, int out_size, void* d_ws, size_t ws_size,
                              hipStream_t stream) {
    const float* x     = (const float*)d_in[0];
    const float* dist  = (const float*)d_in[1];
    const float* vec   = (const float*)d_in[2];
    const float* rbfW  = (const float*)d_in[4];
    const float* rbf_b = (const float*)d_in[5];
    const float* eWin  = (const float*)d_in[6];
    const float* ebin  = (const float*)d_in[7];
    const float* eWh   = (const float*)d_in[8];
    const float* ebh   = (const float*)d_in[9];
    const float* eWout = (const float*)d_in[10];
    const float* ebout = (const float*)d_in[11];
    const float* fWin  = (const float*)d_in[12];
    const float* fbin  = (const float*)d_in[13];
    const float* fWh   = (const float*)d_in[14];
    const float* fbh   = (const float*)d_in[15];
    const float* fWout = (const float*)d_in[16];
    const float* fbout = (const float*)d_in[17];
    float* out = (float*)d_out;

    // workspace carve (3-slab base ~234 MB, proven fits; 4th slab conditional)
    char* p = (char*)d_ws;
    __bf16* WinTcat = (__bf16*)p;
    __bf16* eWinT = WinTcat;          p += (size_t)1024 * 1536 * 2;
    __bf16* fWinT = (__bf16*)p;       p += (size_t)1024 * 1536 * 2;
    __bf16* eWhT0 = (__bf16*)p;       p += (size_t)3 * 1024 * 1024 * 2;
    __bf16* fWhT0 = (__bf16*)p;       p += (size_t)3 * 1024 * 1024 * 2;
    __bf16* xb  = (__bf16*)p;         p += (size_t)256 * 512 * 2;
    __bf16* M1  = (__bf16*)p;         p += (size_t)128 * 512 * 2;
    __bf16* WgT = (__bf16*)p;         p += (size_t)2048 * 128 * 2;
    __bf16* G   = (__bf16*)p;         p += (size_t)32768 * 64 * 2;
    float* P0   = (float*)p;          p += (size_t)256 * 2048 * 4;
    float* P1   = (float*)p;          p += (size_t)256 * 2048 * 4;
    float* dot_e = (float*)p;         p += (size_t)16 * 32768 * 4;
    float* dot_f = (float*)p;         p += (size_t)16 * 32768 * 4;
    const size_t SLAB = (size_t)32768 * 1024 * 2;   // 64 MB
    __bf16* he0 = (__bf16*)p;         p += SLAB;
    __bf16* hf0 = (__bf16*)p;         p += SLAB;
    __bf16* hAe = (__bf16*)p;         p += SLAB;    // serial: shared hAlt
    __bf16* hAf = hAe;
    const bool dualHidden = ((size_t)(p - (char*)d_ws) + SLAB) <= ws_size;
    if (dualHidden) hAf = (__bf16*)p;               // 4th slab fits

    zero_out<<<dim3(4), dim3(256), 0, stream>>>(out, 770);

    // weight prep (merged via grid.z)
    transpose_multi<<<dim3(24, 16, 2), dim3(256), 0, stream>>>(
        eWin, fWin, eWinT, fWinT, 1536, 1024, 1);
    transpose_multi<<<dim3(16, 16, 6), dim3(256), 0, stream>>>(
        eWh, fWh, eWhT0, fWhT0, 1024, 1024, 3);
    f32_to_bf16<<<dim3(128), dim3(256), 0, stream>>>(x, xb, 131072);
    build_M1<<<dim3(128), dim3(256), 0, stream>>>(rbfW, rbf_b, M1);
    build_G<<<dim3(1024), dim3(256), 0, stream>>>(dist, G);

    const dim3 blk(256);
    // P0|P1 merged: x(256x512) @ Win[0:512) / [512:1024) -> f32 (256x2048)
    gemm_k<16, 16, 3, true, 3, false><<<dim3(64), blk, 0, stream>>>(
        xb, xb, WinTcat, WinTcat + 512, 1024, 3072, 2048,
        nullptr, nullptr, nullptr, nullptr, P0, P1,
        nullptr, nullptr, nullptr, nullptr, nullptr, nullptr);
    // WgT(2048x128) = WinTcat[:,1024:1536] @ M1^T (bf16 raw)
    gemm_k<16, 1, 4, false, 3, false><<<dim3(16), blk, 0, stream>>>(
        WinTcat + 1024, nullptr, M1, nullptr, 3072, 1024, 128,
        nullptr, nullptr, WgT, nullptr, nullptr, nullptr,
        nullptr, nullptr, nullptr, nullptr, nullptr, nullptr);
    // layer 0: he0|hf0 = gelu(G @ Wg + bias + P0[i,b] + P1[j,b])
    gemm_k<2, 16, 2, false, 3, true><<<dim3(4096), blk, 0, stream>>>(
        G, nullptr, WgT, nullptr, 128, 256, 1024,
        ebin, fbin, he0, hf0, nullptr, nullptr, P0, P1,
        nullptr, nullptr, nullptr, nullptr);

    if (dualHidden) {
        // both branches per dispatch (4 slabs)
        gemm_k<32, 8, 0, true, 3, true><<<dim3(4096), blk, 0, stream>>>(
            he0, hf0, eWhT0, fWhT0, 2048, 2048, 1024,
            ebh + 0, fbh + 0, hAe, hAf, nullptr, nullptr,
            nullptr, nullptr, nullptr, nullptr, nullptr, nullptr);
        gemm_k<32, 8, 0, true, 3, true><<<dim3(4096), blk, 0, stream>>>(
            hAe, hAf, eWhT0 + (size_t)1048576, fWhT0 + (size_t)1048576,
            2048, 2048, 1024, ebh + 1024, fbh + 1024, he0, hf0,
            nullptr, nullptr, nullptr, nullptr, nullptr, nullptr, nullptr, nullptr);
    } else {
        // branch-serial fallback (3 slabs, hAe==hAf)
        gemm_k<32, 8, 0, false, 3, true><<<dim3(2048), blk, 0, stream>>>(
            he0, nullptr, eWhT0, nullptr, 2048, 2048, 1024,
            ebh + 0, nullptr, hAe, nullptr, nullptr, nullptr,
            nullptr, nullptr, nullptr, nullptr, nullptr, nullptr);
        gemm_k<32, 8, 0, false, 3, true><<<dim3(2048), blk, 0, stream>>>(
            hAe, nullptr, eWhT0 + (size_t)1048576, nullptr, 2048, 2048, 1024,
            ebh + 1024, nullptr, he0, nullptr, nullptr, nullptr,
            nullptr, nullptr, nullptr, nullptr, nullptr, nullptr);
        gemm_k<32, 8, 0, false, 3, true><<<dim3(2048), blk, 0, stream>>>(
            hf0, nullptr, fWhT0, nullptr, 2048, 2048, 1024,
            fbh + 0, nullptr, hAf, nullptr, nullptr, nullptr,
            nullptr, nullptr, nullptr, nullptr, nullptr, nullptr);
        gemm_k<32, 8, 0, false, 3, true><<<dim3(2048), blk, 0, stream>>>(
            hAf, nullptr, fWhT0 + (size_t)1048576, nullptr, 2048, 2048, 1024,
            fbh + 1024, nullptr, hf0, nullptr, nullptr, nullptr,
            nullptr, nullptr, nullptr, nullptr, nullptr, nullptr);
    }
    // merged HEAD (MINW=2: needs ~128-172 VGPR; cap 256 avoids round-6 spill)
    gemm_k<32, 8, 1, true, 2, true><<<dim3(4096), blk, 0, stream>>>(
        he0, hf0, eWhT0 + (size_t)2 * 1048576, fWhT0 + (size_t)2 * 1048576,
        2048, 2048, 1024, ebh + 2048, fbh + 2048,
        nullptr, nullptr, nullptr, nullptr, nullptr, nullptr,
        eWout, fWout, dot_e, dot_f);

    finalize<<<dim3(256), dim3(128), 0, stream>>>(dot_e, dot_f, ebout, fbout, vec, out);
}

// Round 9
// 808.826 us; speedup vs baseline: 2.3147x; 1.3995x over previous
//
#include <hip/hip_runtime.h>
#include <stdint.h>

typedef __bf16 bf16x8 __attribute__((ext_vector_type(8)));
typedef __bf16 bf16x4 __attribute__((ext_vector_type(4)));
typedef float  f32x4  __attribute__((ext_vector_type(4)));
typedef unsigned int u32;

__device__ __forceinline__ void gl_lds16(const void* gptr, void* lptr) {
    __builtin_amdgcn_global_load_lds(
        (const __attribute__((address_space(1))) u32*)gptr,
        (__attribute__((address_space(3))) u32*)lptr,
        16, 0, 0);
}

// Branchless tanh-approx GELU (~10 VALU ops: 1 v_exp, 1 v_rcp) vs erff's ~35.
// Max |delta| vs exact gelu ~3e-4 -- below bf16 output rounding.
__device__ __forceinline__ float gelu_f(float x) {
    float u = 0.7978845608f * x * (1.0f + 0.044715f * x * x);
    float e = __expf(2.0f * u);              // inf for big u -> t=1; 0 for very neg -> t=-1
    float t = 1.0f - 2.0f / (e + 1.0f);
    return 0.5f * x * (1.0f + t);
}

#define MEMFENCE __asm__ __volatile__("" ::: "memory")

__global__ void zero_out(float* __restrict__ o, int n) {
    int i = blockIdx.x * 256 + threadIdx.x;
    if (i < n) o[i] = 0.0f;
}

// ---------------------------------------------------------------------------
// fp32 [K][N] -> bf16 transposed [N][K]; z selects (branch,l) pair
// ---------------------------------------------------------------------------
__global__ __launch_bounds__(256)
void transpose_multi(const float* __restrict__ src0, const float* __restrict__ src1,
                     __bf16* __restrict__ dst0, __bf16* __restrict__ dst1,
                     int K, int Ncols, int perBranch) {
    const int z = blockIdx.z;
    const int branch = z / perBranch;
    const int l = z - branch * perBranch;
    const size_t elems = (size_t)K * Ncols;
    const float* src = (branch ? src1 : src0) + (size_t)l * elems;
    __bf16* dst = (branch ? dst1 : dst0) + (size_t)l * elems;

    __shared__ float tile[64][65];
    const int bk = blockIdx.x * 64;
    const int bn = blockIdx.y * 64;
    const int tid = threadIdx.x;
    const int tr = tid >> 4;
    const int tc = (tid & 15) * 4;
#pragma unroll
    for (int p = 0; p < 4; ++p) {
        const int r = tr + p * 16;
        float4 v = *(const float4*)&src[(size_t)(bk + r) * Ncols + bn + tc];
        tile[r][tc] = v.x; tile[r][tc + 1] = v.y;
        tile[r][tc + 2] = v.z; tile[r][tc + 3] = v.w;
    }
    __syncthreads();
#pragma unroll
    for (int p = 0; p < 4; ++p) {
        const int rn = tr + p * 16;
        bf16x4 o;
        o[0] = (__bf16)tile[tc + 0][rn];
        o[1] = (__bf16)tile[tc + 1][rn];
        o[2] = (__bf16)tile[tc + 2][rn];
        o[3] = (__bf16)tile[tc + 3][rn];
        *(bf16x4*)&dst[(size_t)(bn + rn) * K + bk + tc] = o;
    }
}

__global__ void f32_to_bf16(const float* __restrict__ s, __bf16* __restrict__ d, int n) {
    int idx = blockIdx.x * 256 + threadIdx.x;
    if (idx * 4 < n) {
        float4 v = *(const float4*)(s + idx * 4);
        bf16x4 o;
        o[0] = (__bf16)v.x; o[1] = (__bf16)v.y; o[2] = (__bf16)v.z; o[3] = (__bf16)v.w;
        *(bf16x4*)(d + idx * 4) = o;
    }
}

// M1 bf16 [128][512]: rows 0..49 = rbf_W, row 50 = rbf_b, rows 51..127 = 0
__global__ void build_M1(const float* __restrict__ rbfW, const float* __restrict__ rbf_b,
                         __bf16* __restrict__ M1) {
    int t = blockIdx.x * 256 + threadIdx.x;
    int r = t >> 8;
    int c = (t & 255) * 2;
    float v0 = 0.f, v1 = 0.f;
    if (r < 50)       { v0 = rbfW[r * 512 + c]; v1 = rbfW[r * 512 + c + 1]; }
    else if (r == 50) { v0 = rbf_b[c];          v1 = rbf_b[c + 1]; }
    M1[r * 512 + c] = (__bf16)v0;
    M1[r * 512 + c + 1] = (__bf16)v1;
}

// G bf16 [32768][64]: cols 0..49 = exp(coeff*(dist-k*sp)^2), col 50 = 1, rest 0
__global__ __launch_bounds__(256)
void build_G(const float* __restrict__ dist, __bf16* __restrict__ G) {
    const int t = threadIdx.x;
    const int row = blockIdx.x * 32 + (t >> 3);
    const int c0 = (t & 7) * 8;
    const float sp = 12.0f / 49.0f;
    const float coeff = -0.5f / (sp * sp);
    const float d = dist[row];
    bf16x8 v;
#pragma unroll
    for (int q = 0; q < 8; ++q) {
        const int k = c0 + q;
        float val;
        if (k < 50)       { float tt = d - (float)k * sp; val = __expf(coeff * tt * tt); }
        else if (k == 50) val = 1.0f;
        else              val = 0.0f;
        v[q] = (__bf16)val;
    }
    *(bf16x8*)(G + (size_t)row * 64 + c0) = v;
}

// ---------------------------------------------------------------------------
// 128x128-tile MFMA GEMM. 3-stage LDS pipeline, ONE barrier per K-step.
// SWZ: XCD-aware decode — all NBN bn-siblings of one A-panel land consecutive
// on ONE XCD (blk%8 = XCD round-robin): panel fetched once, N-1 L2 hits.
// Epilogue: per-ni batched residual prefetch (16 indep loads overlap gelu).
// MODE 0 HID : C = gelu(acc+bias)+A
// MODE 1 HEAD: rowdot(gelu(acc+bias)+A, wout) -> dot[(bn*2+wn)*32768+m]
// MODE 2 L0  : gelu(acc + bias + P0 + P1) -> he0/hf0 (side = bn>=8)
// MODE 3 RAWF32 : Cf = acc
// MODE 4 RAWBF16: C0 = (bf16)acc
// ---------------------------------------------------------------------------
template <int NK, int NBN, int MODE, bool DUAL, int MINW, bool SWZ>
__global__ __launch_bounds__(256, MINW)
void gemm_k(const __bf16* __restrict__ A0, const __bf16* __restrict__ A1,
            const __bf16* __restrict__ B0, const __bf16* __restrict__ B1,
            int lda, int ldb, int ldc,
            const float* __restrict__ bias0, const float* __restrict__ bias1,
            __bf16* __restrict__ C0, __bf16* __restrict__ C1,
            float* __restrict__ Cf0, float* __restrict__ Cf1,
            const float* __restrict__ P0, const float* __restrict__ P1,
            const float* __restrict__ wout0, const float* __restrict__ wout1,
            float* __restrict__ dot0, float* __restrict__ dot1) {
    constexpr int NBS = (NBN == 16) ? 4 : (NBN == 8) ? 3 : 0;
    __shared__ __align__(16) __bf16 As[3][128 * 32];
    __shared__ __align__(16) __bf16 Bs[3][128 * 32];

    const int tid = threadIdx.x;
    int bn, bm, branch = 0;
    if constexpr (SWZ) {
        const int x = blockIdx.x & 7;
        const int slot = blockIdx.x >> 3;
        bn = slot & (NBN - 1);
        int grp = x + ((slot >> NBS) << 3);
        if constexpr (DUAL) {
            const int half = (gridDim.x >> NBS) >> 1;   // total groups / 2
            branch = (grp >= half);
            if (branch) grp -= half;
        }
        bm = grp;
    } else {
        int f2 = blockIdx.x;
        if constexpr (DUAL) {
            const int half = gridDim.x >> 1;
            branch = (f2 >= half);
            if (branch) f2 -= half;
        }
        bn = f2 & (NBN - 1);
        bm = f2 >> NBS;
    }
    const int w = tid >> 6;
    const int lane = tid & 63;

    const __bf16* Ab = (DUAL && branch) ? A1 : A0;
    const __bf16* Bb = (DUAL && branch) ? B1 : B0;

    const int r0 = tid >> 2;
    const int s0 = tid & 3;
    const char* gA0 = (const char*)Ab + (size_t)(bm * 128 + r0) * lda + s0 * 16;
    const char* gA1 = gA0 + (size_t)64 * lda;
    const char* gB0 = (const char*)Bb + (size_t)(bn * 128 + r0) * ldb + s0 * 16;
    const char* gB1 = gB0 + (size_t)64 * ldb;

    char* lA0 = (char*)&As[0][0] + w * 1024;
    char* lA1 = (char*)&As[1][0] + w * 1024;
    char* lA2 = (char*)&As[2][0] + w * 1024;
    char* lB0 = (char*)&Bs[0][0] + w * 1024;
    char* lB1 = (char*)&Bs[1][0] + w * 1024;
    char* lB2 = (char*)&Bs[2][0] + w * 1024;

    const int wm = (w >> 1) & 1;
    const int wn = w & 1;
    const int lm = lane & 15;
    const int ko = (lane >> 4) << 3;
    const int fo = (wm * 64 + lm) * 32 + ko;
    const int go = (wn * 64 + lm) * 32 + ko;
    const __bf16* pA0 = &As[0][0] + fo;
    const __bf16* pA1 = &As[1][0] + fo;
    const __bf16* pA2 = &As[2][0] + fo;
    const __bf16* pB0 = &Bs[0][0] + go;
    const __bf16* pB1 = &Bs[1][0] + go;
    const __bf16* pB2 = &Bs[2][0] + go;

    f32x4 acc[4][4];
    const f32x4 zero = {0.0f, 0.0f, 0.0f, 0.0f};
#pragma unroll
    for (int i = 0; i < 4; ++i)
#pragma unroll
        for (int j = 0; j < 4; ++j) acc[i][j] = zero;

    auto stage = [&](int buf) {   // buf literal at every call site
        char* la = (buf == 0) ? lA0 : (buf == 1) ? lA1 : lA2;
        char* lb = (buf == 0) ? lB0 : (buf == 1) ? lB1 : lB2;
        gl_lds16(gA0, la); gl_lds16(gA1, la + 4096);
        gl_lds16(gB0, lb); gl_lds16(gB1, lb + 4096);
        gA0 += 64; gA1 += 64; gB0 += 64; gB1 += 64;
    };
    auto compute = [&](int buf) {
        const __bf16* pa = (buf == 0) ? pA0 : (buf == 1) ? pA1 : pA2;
        const __bf16* pb = (buf == 0) ? pB0 : (buf == 1) ? pB1 : pB2;
        bf16x8 af[4], bfg[4];
#pragma unroll
        for (int i = 0; i < 4; ++i) {
            af[i]  = *(const bf16x8*)(pa + i * 512);
            bfg[i] = *(const bf16x8*)(pb + i * 512);
        }
#pragma unroll
        for (int mi = 0; mi < 4; ++mi)
#pragma unroll
            for (int ni = 0; ni < 4; ++ni)
                acc[mi][ni] = __builtin_amdgcn_mfma_f32_16x16x32_bf16(
                    af[mi], bfg[ni], acc[mi][ni], 0, 0, 0);
    };
    auto iterstep = [&](int cbuf, int sbuf) {
        MEMFENCE;
        __builtin_amdgcn_s_waitcnt(0xF74);   // vmcnt(4): cbuf's 4 loads landed
        __builtin_amdgcn_s_barrier();
        MEMFENCE;
        compute(cbuf);
        MEMFENCE;
        stage(sbuf);                         // overwrites buffer computed last
        MEMFENCE;                            // iter -- barrier above separates
    };

    stage(0);
    stage(1);
    constexpr int NIT = NK - 2;
    constexpr int NG = NIT / 3;
    constexpr int NR = NIT % 3;
    for (int g = 0; g < NG; ++g) {           // runtime loop, constant indices
        iterstep(0, 2);
        iterstep(1, 0);
        iterstep(2, 1);
    }
    if constexpr (NR >= 1) iterstep(0, 2);
    if constexpr (NR >= 2) iterstep(1, 0);
    // tails (no more stages)
    MEMFENCE;
    __builtin_amdgcn_s_waitcnt(0xF74);       // vmcnt(4)
    __builtin_amdgcn_s_barrier();
    MEMFENCE;
    compute((NK - 2) % 3);
    MEMFENCE;
    __builtin_amdgcn_s_waitcnt(0xF70);       // vmcnt(0)
    __builtin_amdgcn_s_barrier();
    MEMFENCE;
    compute((NK - 1) % 3);

    // epilogue: C/D layout col = lane&15, row = (lane>>4)*4 + reg
    const int col0 = bn * 128 + wn * 64 + lm;
    const int row0 = bm * 128 + wm * 64 + ((lane >> 4) << 2);
    const int ldaE = lda >> 1;

    float rowdot[16];
    if constexpr (MODE == 1) {
#pragma unroll
        for (int q = 0; q < 16; ++q) rowdot[q] = 0.0f;
    }

    const bool side = (MODE == 2) && (bn >= 8);
    const float* bp = (MODE == 2) ? (side ? bias1 : bias0)
                                  : ((DUAL && branch) ? bias1 : bias0);
    __bf16* Cout = (MODE == 2) ? (side ? C1 : C0)
                               : ((DUAL && branch) ? C1 : C0);
    const float* woutb = (MODE == 1) ? ((DUAL && branch) ? wout1 : wout0) : nullptr;

#pragma unroll
    for (int ni = 0; ni < 4; ++ni) {
        const int gn = col0 + ni * 16;
        const int gnl = (MODE == 2) ? (gn & 1023) : gn;
        float bv = 0.0f;
        if constexpr (MODE <= 2) bv = bp[gnl];
        float wv = 0.0f;
        if constexpr (MODE == 1) wv = woutb[gn];

        // batched prefetch: 16 independent loads issued before any gelu math
        float res[16];
        if constexpr (MODE == 0 || MODE == 1) {
#pragma unroll
            for (int mi = 0; mi < 4; ++mi)
#pragma unroll
                for (int rr = 0; rr < 4; ++rr)
                    res[mi * 4 + rr] =
                        (float)Ab[(size_t)(row0 + mi * 16 + rr) * ldaE + gn];
        } else if constexpr (MODE == 2) {
#pragma unroll
            for (int mi = 0; mi < 4; ++mi)
#pragma unroll
                for (int rr = 0; rr < 4; ++rr) {
                    const int gm = row0 + mi * 16 + rr;
                    const int p0row = ((gm >> 8) << 1) | (gm & 1);
                    const int p1row = gm & 255;
                    res[mi * 4 + rr] = P0[(size_t)p0row * 2048 + gn]
                                     + P1[(size_t)p1row * 2048 + gn];
                }
        }
        MEMFENCE;

#pragma unroll
        for (int mi = 0; mi < 4; ++mi) {
#pragma unroll
            for (int rr = 0; rr < 4; ++rr) {
                const int gm = row0 + mi * 16 + rr;
                const float a = acc[mi][ni][rr];
                if constexpr (MODE == 0) {
                    float v = gelu_f(a + bv) + res[mi * 4 + rr];
                    Cout[(size_t)gm * ldc + gn] = (__bf16)v;
                } else if constexpr (MODE == 1) {
                    float v = gelu_f(a + bv) + res[mi * 4 + rr];
                    rowdot[mi * 4 + rr] += v * wv;
                } else if constexpr (MODE == 2) {
                    float v = a + bv + res[mi * 4 + rr];
                    Cout[(size_t)gm * ldc + gnl] = (__bf16)gelu_f(v);
                } else if constexpr (MODE == 3) {
                    float* Cfw = (DUAL && branch) ? Cf1 : Cf0;
                    Cfw[(size_t)gm * ldc + gn] = a;
                } else {
                    C0[(size_t)gm * ldc + gn] = (__bf16)a;
                }
            }
        }
    }

    if constexpr (MODE == 1) {
#pragma unroll
        for (int s = 1; s < 16; s <<= 1)
#pragma unroll
            for (int q = 0; q < 16; ++q) rowdot[q] += __shfl_xor(rowdot[q], s);
        if (lm == 0) {
            float* dotb = (DUAL && branch) ? dot1 : dot0;
            float* dp = dotb + (size_t)(bn * 2 + wn) * 32768 + row0;
#pragma unroll
            for (int q = 0; q < 16; ++q)
                dp[(q >> 2) * 16 + (q & 3)] = rowdot[q];
        }
    }
}

// ---------------------------------------------------------------------------
// finalize: sum 16 (bn,wn)-partials per row; block = (b,j), reduce over i
// ---------------------------------------------------------------------------
__global__ __launch_bounds__(128)
void finalize(const float* __restrict__ dot_e, const float* __restrict__ dot_f,
              const float* __restrict__ eb, const float* __restrict__ fb,
              const float* __restrict__ vec, float* __restrict__ out) {
    const int bj = blockIdx.x;
    const int bb = bj >> 7, jj = bj & 127;
    const int i = threadIdx.x;
    const int m = (i * 128 + jj) * 2 + bb;
    float e = eb[0], f = fb[0];
#pragma unroll
    for (int s = 0; s < 16; ++s) {
        e += dot_e[(size_t)s * 32768 + m];
        f += dot_f[(size_t)s * 32768 + m];
    }
    f *= (1.0f / 60.0f);
    float fx = f * vec[(size_t)m * 3 + 0];
    float fy = f * vec[(size_t)m * 3 + 1];
    float fz = f * vec[(size_t)m * 3 + 2];
#pragma unroll
    for (int off = 32; off > 0; off >>= 1) {
        e  += __shfl_down(e, off);
        fx += __shfl_down(fx, off);
        fy += __shfl_down(fy, off);
        fz += __shfl_down(fz, off);
    }
    __shared__ float red[2][4];
    const int wv = i >> 6, lane = i & 63;
    if (lane == 0) { red[wv][0] = e; red[wv][1] = fx; red[wv][2] = fy; red[wv][3] = fz; }
    __syncthreads();
    if (i == 0) {
        atomicAdd(&out[bb], (red[0][0] + red[1][0]) * (1.0f / 3600.0f));
        float* fo = out + 2 + bj * 3;
        fo[0] = red[0][1] + red[1][1];
        fo[1] = red[0][2] + red[1][2];
        fo[2] = red[0][3] + red[1][3];
    }
}

// ---------------------------------------------------------------------------
extern "C" void kernel_launch(void* const* d_in, const int* in_sizes, int n_in,
                              void* d_out, int out_size, void* d_ws, size_t ws_size,
                              hipStream_t stream) {
    const float* x     = (const float*)d_in[0];
    const float* dist  = (const float*)d_in[1];
    const float* vec   = (const float*)d_in[2];
    const float* rbfW  = (const float*)d_in[4];
    const float* rbf_b = (const float*)d_in[5];
    const float* eWin  = (const float*)d_in[6];
    const float* ebin  = (const float*)d_in[7];
    const float* eWh   = (const float*)d_in[8];
    const float* ebh   = (const float*)d_in[9];
    const float* eWout = (const float*)d_in[10];
    const float* ebout = (const float*)d_in[11];
    const float* fWin  = (const float*)d_in[12];
    const float* fbin  = (const float*)d_in[13];
    const float* fWh   = (const float*)d_in[14];
    const float* fbh   = (const float*)d_in[15];
    const float* fWout = (const float*)d_in[16];
    const float* fbout = (const float*)d_in[17];
    float* out = (float*)d_out;

    // workspace carve (3-slab base ~234 MB, proven fits; 4th slab conditional)
    char* p = (char*)d_ws;
    __bf16* WinTcat = (__bf16*)p;
    __bf16* eWinT = WinTcat;          p += (size_t)1024 * 1536 * 2;
    __bf16* fWinT = (__bf16*)p;       p += (size_t)1024 * 1536 * 2;
    __bf16* eWhT0 = (__bf16*)p;       p += (size_t)3 * 1024 * 1024 * 2;
    __bf16* fWhT0 = (__bf16*)p;       p += (size_t)3 * 1024 * 1024 * 2;
    __bf16* xb  = (__bf16*)p;         p += (size_t)256 * 512 * 2;
    __bf16* M1  = (__bf16*)p;         p += (size_t)128 * 512 * 2;
    __bf16* WgT = (__bf16*)p;         p += (size_t)2048 * 128 * 2;
    __bf16* G   = (__bf16*)p;         p += (size_t)32768 * 64 * 2;
    float* P0   = (float*)p;          p += (size_t)256 * 2048 * 4;
    float* P1   = (float*)p;          p += (size_t)256 * 2048 * 4;
    float* dot_e = (float*)p;         p += (size_t)16 * 32768 * 4;
    float* dot_f = (float*)p;         p += (size_t)16 * 32768 * 4;
    const size_t SLAB = (size_t)32768 * 1024 * 2;   // 64 MB
    __bf16* he0 = (__bf16*)p;         p += SLAB;
    __bf16* hf0 = (__bf16*)p;         p += SLAB;
    __bf16* hAe = (__bf16*)p;         p += SLAB;    // serial: shared hAlt
    __bf16* hAf = hAe;
    const bool dualHidden = ((size_t)(p - (char*)d_ws) + SLAB) <= ws_size;
    if (dualHidden) hAf = (__bf16*)p;               // 4th slab fits

    zero_out<<<dim3(4), dim3(256), 0, stream>>>(out, 770);

    // weight prep (merged via grid.z)
    transpose_multi<<<dim3(24, 16, 2), dim3(256), 0, stream>>>(
        eWin, fWin, eWinT, fWinT, 1536, 1024, 1);
    transpose_multi<<<dim3(16, 16, 6), dim3(256), 0, stream>>>(
        eWh, fWh, eWhT0, fWhT0, 1024, 1024, 3);
    f32_to_bf16<<<dim3(128), dim3(256), 0, stream>>>(x, xb, 131072);
    build_M1<<<dim3(128), dim3(256), 0, stream>>>(rbfW, rbf_b, M1);
    build_G<<<dim3(1024), dim3(256), 0, stream>>>(dist, G);

    const dim3 blk(256);
    // P0|P1 merged: x(256x512) @ Win[0:512) / [512:1024) -> f32 (256x2048)
    gemm_k<16, 16, 3, true, 3, false><<<dim3(64), blk, 0, stream>>>(
        xb, xb, WinTcat, WinTcat + 512, 1024, 3072, 2048,
        nullptr, nullptr, nullptr, nullptr, P0, P1,
        nullptr, nullptr, nullptr, nullptr, nullptr, nullptr);
    // WgT(2048x128) = WinTcat[:,1024:1536] @ M1^T (bf16 raw)
    gemm_k<16, 1, 4, false, 3, false><<<dim3(16), blk, 0, stream>>>(
        WinTcat + 1024, nullptr, M1, nullptr, 3072, 1024, 128,
        nullptr, nullptr, WgT, nullptr, nullptr, nullptr,
        nullptr, nullptr, nullptr, nullptr, nullptr, nullptr);
    // layer 0: he0|hf0 = gelu(G @ Wg + bias + P0[i,b] + P1[j,b])
    gemm_k<2, 16, 2, false, 3, true><<<dim3(4096), blk, 0, stream>>>(
        G, nullptr, WgT, nullptr, 128, 256, 1024,
        ebin, fbin, he0, hf0, nullptr, nullptr, P0, P1,
        nullptr, nullptr, nullptr, nullptr);

    if (dualHidden) {
        // both branches per dispatch (4 slabs)
        gemm_k<32, 8, 0, true, 3, true><<<dim3(4096), blk, 0, stream>>>(
            he0, hf0, eWhT0, fWhT0, 2048, 2048, 1024,
            ebh + 0, fbh + 0, hAe, hAf, nullptr, nullptr,
            nullptr, nullptr, nullptr, nullptr, nullptr, nullptr);
        gemm_k<32, 8, 0, true, 3, true><<<dim3(4096), blk, 0, stream>>>(
            hAe, hAf, eWhT0 + (size_t)1048576, fWhT0 + (size_t)1048576,
            2048, 2048, 1024, ebh + 1024, fbh + 1024, he0, hf0,
            nullptr, nullptr, nullptr, nullptr, nullptr, nullptr, nullptr, nullptr);
    } else {
        // branch-serial fallback (3 slabs, hAe==hAf)
        gemm_k<32, 8, 0, false, 3, true><<<dim3(2048), blk, 0, stream>>>(
            he0, nullptr, eWhT0, nullptr, 2048, 2048, 1024,
            ebh + 0, nullptr, hAe, nullptr, nullptr, nullptr,
            nullptr, nullptr, nullptr, nullptr, nullptr, nullptr);
        gemm_k<32, 8, 0, false, 3, true><<<dim3(2048), blk, 0, stream>>>(
            hAe, nullptr, eWhT0 + (size_t)1048576, nullptr, 2048, 2048, 1024,
            ebh + 1024, nullptr, he0, nullptr, nullptr, nullptr,
            nullptr, nullptr, nullptr, nullptr, nullptr, nullptr);
        gemm_k<32, 8, 0, false, 3, true><<<dim3(2048), blk, 0, stream>>>(
            hf0, nullptr, fWhT0, nullptr, 2048, 2048, 1024,
            fbh + 0, nullptr, hAf, nullptr, nullptr, nullptr,
            nullptr, nullptr, nullptr, nullptr, nullptr, nullptr);
        gemm_k<32, 8, 0, false, 3, true><<<dim3(2048), blk, 0, stream>>>(
            hAf, nullptr, fWhT0 + (size_t)1048576, nullptr, 2048, 2048, 1024,
            fbh + 1024, nullptr, hf0, nullptr, nullptr, nullptr,
            nullptr, nullptr, nullptr, nullptr, nullptr, nullptr);
    }
    // merged HEAD (MINW=2: epilogue-heavy; cap 256 avoids round-6 spill)
    gemm_k<32, 8, 1, true, 2, true><<<dim3(4096), blk, 0, stream>>>(
        he0, hf0, eWhT0 + (size_t)2 * 1048576, fWhT0 + (size_t)2 * 1048576,
        2048, 2048, 1024, ebh + 2048, fbh + 2048,
        nullptr, nullptr, nullptr, nullptr, nullptr, nullptr,
        eWout, fWout, dot_e, dot_f);

    finalize<<<dim3(256), dim3(128), 0, stream>>>(dot_e, dot_f, ebout, fbout, vec, out);
}